// Round 10
// baseline (421.738 us; speedup 1.0000x reference)
//
#include <hip/hip_runtime.h>
#include <hip/hip_bf16.h>

typedef unsigned short u16;
typedef unsigned int   u32;
typedef __attribute__((ext_vector_type(8))) short bf16x8;
typedef __attribute__((ext_vector_type(4))) float f32x4;

#define MFMA16(a,b,c) __builtin_amdgcn_mfma_f32_16x16x32_bf16((a),(b),(c),0,0,0)

__device__ __forceinline__ float b2f(u32 h){ return __uint_as_float(h<<16); }
__device__ __forceinline__ u16 f2b(float f){
  u32 u = __float_as_uint(f);
  return (u16)((u + 0x7FFFu + ((u>>16)&1u))>>16);
}
// HW packed convert: v_cvt_pk_bf16_f32 (RNE)
__device__ __forceinline__ u32 pk2f(float a,float b){
  __hip_bfloat162 h = __float22bfloat162_rn(float2{a,b});
  return *reinterpret_cast<u32*>(&h);
}
__device__ __forceinline__ u32 umin32(u32 a,u32 b){ return a<b?a:b; }
__device__ __forceinline__ u32 umax32(u32 a,u32 b){ return a>b?a:b; }

// 16-lane row-sum on the VALU pipe via DPP row_ror
template<int CTRL>
__device__ __forceinline__ float dpp_add(float x){
  int t = __builtin_amdgcn_update_dpp(0, __float_as_int(x), CTRL, 0xF, 0xF, true);
  return x + __int_as_float(t);
}
__device__ __forceinline__ float rowsum16(float x){
  x = dpp_add<0x121>(x);
  x = dpp_add<0x122>(x);
  x = dpp_add<0x124>(x);
  x = dpp_add<0x128>(x);
  return x;
}

__device__ __forceinline__ void async_copy16(const void* g, void* l){
  __builtin_amdgcn_global_load_lds((const __attribute__((address_space(1))) u32*)g,
                                   (__attribute__((address_space(3))) u32*)l, 16, 0, 0);
}

// ---------------- workspace layout (bytes) ----------------
#define OFF_IDX    0ull
#define OFF_WQKV   3178496ull
#define OFF_WA1    3571712ull
#define OFF_WA2    3702784ull
#define OFF_WP2    3833856ull
#define OFF_WPROJ  3964928ull
#define OFF_WPOST  4096000ull
#define OFF_MCOMB  4128768ull
#define OFF_INP    4259840ull
#define OFF_LNQKV  37814272ull
#define OFF_QA     62980096ull
#define OFF_KA     71368704ull
#define OFF_RES    79757312ull
#define OFF_D1     88145920ull
#define WS_NEED    104923136ull
#define OFF_WP1PK  OFF_D1

// ---------------- kNN insertion: a[j] = med3(a[j-1], key, a[j]) ----------------
// Given sorted a[0..15] ascending, min(max(a[j-1],key),a[j]) == median3 of the
// three. v_med3_u32 replaces the 2-op min/max pair -> 16 instr per candidate.
__device__ __forceinline__ void ins16(u32 (&a)[16], u32 key){
  #pragma unroll
  for (int j = 15; j >= 1; --j){
    u32 r;
    asm("v_med3_u32 %0, %1, %2, %3" : "=v"(r) : "v"(a[j-1]), "v"(key), "v"(a[j]));
    a[j] = r;
  }
  a[0] = umin32(a[0], key);
}

__device__ __forceinline__ float dist2(float ax,float ay,float az,float bx,float by,float bz){
  const float dx = ax-bx, dy = ay-by, dz = az-bz;
  return __fmaf_rn(dx,dx, __fmaf_rn(dy,dy, dz*dz));
}

// ---------------- prep (weights): converts + wp1 pack + mcomb + inp GEMM ----------------
__global__ __launch_bounds__(256,2) void prep_w_k(
    const float* __restrict__ feat,
    const float* __restrict__ wpre, const float* __restrict__ bpre,
    const float* __restrict__ wq, const float* __restrict__ wk, const float* __restrict__ wv,
    const float* __restrict__ wa1, const float* __restrict__ wa2, const float* __restrict__ wp2,
    const float* __restrict__ wproj, const float* __restrict__ wpost,
    const float* __restrict__ wp1,
    u16* __restrict__ dwqkv, u16* __restrict__ dwa1, u16* __restrict__ dwa2,
    u16* __restrict__ dwp2, u16* __restrict__ dwproj, u16* __restrict__ dwpost,
    u16* __restrict__ dwp1pk, u16* __restrict__ dmcomb,
    u16* __restrict__ dinp){
  __shared__ __attribute__((aligned(16))) char smem[36864];
  const int bid = blockIdx.x, tid = threadIdx.x;
  if (bid < 1856){
    int id = bid*256 + tid;
    const float* s; u16* d; int off;
    if      (id <  65536){ s=wq;    d=dwqkv;        off=id; }
    else if (id < 131072){ s=wk;    d=dwqkv+65536;  off=id-65536; }
    else if (id < 196608){ s=wv;    d=dwqkv+131072; off=id-131072; }
    else if (id < 262144){ s=wa1;   d=dwa1;         off=id-196608; }
    else if (id < 327680){ s=wa2;   d=dwa2;         off=id-262144; }
    else if (id < 393216){ s=wp2;   d=dwp2;         off=id-327680; }
    else if (id < 458752){ s=wproj; d=dwproj;       off=id-393216; }
    else                 { s=wpost; d=dwpost;       off=id-458752; }
    d[off] = f2b(s[off]);
  } else if (bid == 1856){
    const int h = tid;
    const float w0 = wp1[h*3], w1 = wp1[h*3+1], w2 = wp1[h*3+2];
    uint4 a; a.x = pk2f(w0,w1); a.y = pk2f(w2,0.f); a.z = 0u; a.w = 0u;
    uint4 z; z.x = z.y = z.z = z.w = 0u;
    *(uint4*)&dwp1pk[h*32]    = a;
    *(uint4*)&dwp1pk[h*32+8]  = z;
    *(uint4*)&dwp1pk[h*32+16] = z;
    *(uint4*)&dwp1pk[h*32+24] = z;
  } else if (bid < 2113){
    const int f = bid - 1857, h = tid;
    float acc = 0.f;
    #pragma unroll 4
    for (int j = 0; j < 256; ++j) acc = __fmaf_rn(wa1[f*256+j], wp2[j*256+h], acc);
    dmcomb[f*256+h] = f2b(acc);
  } else {
    // ---- inp = feat @ W_pre.T + b_pre (K=64), 128x128 tile
    u16* As = (u16*)smem;            // [128][72]
    u16* Bs = (u16*)smem + 9216;     // [128][72]
    const int tb = bid - 2113;
    const int mb = tb >> 1, nb = tb & 1;
    #pragma unroll
    for (int i = 0; i < 32; ++i){
      const int e = i*256 + tid;
      const int row = e >> 6, k = e & 63;
      As[row*72+k] = f2b(feat[(size_t)(mb*128)*64 + e]);
      Bs[row*72+k] = f2b(wpre[(size_t)(nb*128)*64 + e]);
    }
    __syncthreads();
    const int lane = tid & 63, w = tid >> 6;
    const int mrow = lane & 15, quad = lane >> 4;
    const int wr = (w&1)*64, wc = (w>>1)*64;
    f32x4 acc[4][4];
    #pragma unroll
    for (int i=0;i<4;++i)
      #pragma unroll
      for (int j=0;j<4;++j)
        #pragma unroll
        for (int r=0;r<4;++r) acc[i][j][r] = 0.f;
    #pragma unroll
    for (int ks = 0; ks < 2; ++ks){
      const int koff = ks*32 + quad*8;
      bf16x8 af[4], bf[4];
      #pragma unroll
      for (int rt=0;rt<4;++rt) af[rt] = *(const bf16x8*)&As[(wr+rt*16+mrow)*72 + koff];
      #pragma unroll
      for (int ct=0;ct<4;++ct) bf[ct] = *(const bf16x8*)&Bs[(wc+ct*16+mrow)*72 + koff];
      #pragma unroll
      for (int rt=0;rt<4;++rt)
        #pragma unroll
        for (int ct=0;ct<4;++ct) acc[rt][ct] = MFMA16(af[rt], bf[ct], acc[rt][ct]);
    }
    #pragma unroll
    for (int rt=0;rt<4;++rt)
      #pragma unroll
      for (int ct=0;ct<4;++ct){
        const size_t row0 = (size_t)mb*128 + wr + rt*16 + quad*4;
        const int col = nb*128 + wc + ct*16 + mrow;
        const float bv = bpre[col];
        #pragma unroll
        for (int r=0;r<4;++r) dinp[(row0+r)*256 + col] = f2b(acc[rt][ct][r] + bv);
      }
  }
}

// ---------------- merged GEMM+LN / kNN kernel ----------------
// Grid dim3(7,1,256): blockIdx.x = role (0..2 gemm z-planes, 3..6 kNN tile groups),
// blockIdx.z = tile index. x-fastest dispatch interleaves 3 gemm + 4 knn blocks
// per group -> knn's VALU/LDS work overlaps gemm's MFMA/HBM work (they were
// serial launches before; knn is independent of gemm inputs).
// kNN body = round-9-validated code under tid<256 guards (wave-uniform; barriers
// at top level, executed by all 512 threads).
#define LNP 264
__global__ __launch_bounds__(512,2) void gemmknn_k(
    const u16* __restrict__ inp, const u16* __restrict__ wqkv, const u16* __restrict__ wa1,
    u16* __restrict__ qa, u16* __restrict__ ka, u16* __restrict__ lnqkv,
    const float* __restrict__ g, const float* __restrict__ bta,
    const float* __restrict__ xyz, int* __restrict__ idxout){
  __shared__ __attribute__((aligned(16))) char smem[54784];
  const int zsel = blockIdx.x;     // 0..6
  const int xb   = blockIdx.z;     // 0..255
  const int tid  = threadIdx.x;
  if (zsel >= 3){
    // ---------------- kNN path (one 16-query tile per block) ----------------
    float* sx = (float*)smem;              // [16][260]
    float* sy = sx + 4160;
    float* sz = sy + 4160;                 // ends at byte 49920
    int* lcnt   = (int*)(smem + 49920);
    int* tcnt   = (int*)(smem + 49984);
    u32* tbuf   = (u32*)(smem + 50048);
    int* tiebuf = (int*)(smem + 50112);
    const int tile = (zsel - 3)*256 + xb;  // 0..1023
    const int b  = tile >> 8;
    const int n0 = (tile & 255) << 4;
    const float* base = xyz + (size_t)b*12288;
    if (tid < 256){
      #pragma unroll
      for (int i = 0; i < 12; ++i){
        const float4 v = *(const float4*)(base + tid*48 + i*4);
        const float vv[4] = {v.x, v.y, v.z, v.w};
        #pragma unroll
        for (int j = 0; j < 4; ++j){
          const int e = i*4 + j;
          const int c = e % 3;
          const int m = tid*16 + e/3;
          float* arr = (c==0)?sx:((c==1)?sy:sz);
          arr[(m>>8)*260 + (m&255)] = vv[j];
        }
      }
      if (tid < 16){ lcnt[tid] = 0; tcnt[tid] = 0; }
    }
    __syncthreads();
    const int qi = (tid >> 4) & 15, p = tid & 15;
    const int n = n0 + qi;
    u32 a[16];
    const float* px = sx + p*260;
    const float* py = sy + p*260;
    const float* pz = sz + p*260;
    float qx = 0.f, qy = 0.f, qz = 0.f;
    if (tid < 256){
      qx = sx[(n>>8)*260 + (n&255)];
      qy = sy[(n>>8)*260 + (n&255)];
      qz = sz[(n>>8)*260 + (n&255)];
      #pragma unroll
      for (int j = 0; j < 16; ++j) a[j] = 0xFFFFFFFFu;
      #pragma unroll 2
      for (int i4 = 0; i4 < 64; ++i4){
        const float4 x4 = *(const float4*)(px + i4*4);
        const float4 y4 = *(const float4*)(py + i4*4);
        const float4 z4 = *(const float4*)(pz + i4*4);
        ins16(a, __float_as_uint(dist2(x4.x,y4.x,z4.x,qx,qy,qz)));
        ins16(a, __float_as_uint(dist2(x4.y,y4.y,z4.y,qx,qy,qz)));
        ins16(a, __float_as_uint(dist2(x4.z,y4.z,z4.z,qx,qy,qz)));
        ins16(a, __float_as_uint(dist2(x4.w,y4.w,z4.w,qx,qy,qz)));
      }
      #pragma unroll
      for (int s = 8; s >= 1; s >>= 1){
        u32 o[16];
        #pragma unroll
        for (int j = 0; j < 16; ++j) o[j] = __shfl_down(a[j], (unsigned)s, 64);
        if (p < s){
          #pragma unroll
          for (int j = 0; j < 16; ++j) ins16(a, o[j]);
        }
      }
      if (p == 0) tbuf[qi] = a[15];
    }
    __syncthreads();
    if (tid < 256){
      const u32 T = tbuf[qi];
      int* orow = idxout + ((size_t)(b<<12)+n)*16;
      const int gbase = p*256;
      for (int i4 = 0; i4 < 64; ++i4){
        const float4 x4 = *(const float4*)(px + i4*4);
        const float4 y4 = *(const float4*)(py + i4*4);
        const float4 z4 = *(const float4*)(pz + i4*4);
        const float xv[4] = {x4.x,x4.y,x4.z,x4.w};
        const float yv[4] = {y4.x,y4.y,y4.z,y4.w};
        const float zv[4] = {z4.x,z4.y,z4.z,z4.w};
        #pragma unroll
        for (int j = 0; j < 4; ++j){
          const float d2 = dist2(xv[j],yv[j],zv[j],qx,qy,qz);
          const u32 kb = __float_as_uint(d2);
          if (kb < T){
            const int pos = atomicAdd(&lcnt[qi],1);
            if (pos < 16) orow[pos] = gbase + i4*4 + j;
          } else if (kb == T){
            const int t = atomicAdd(&tcnt[qi],1);
            if (t < 16) tiebuf[qi*16+t] = gbase + i4*4 + j;
          }
        }
      }
    }
    __syncthreads();
    if (tid < 256 && p == 0){
      int* orow = idxout + ((size_t)(b<<12)+n)*16;
      int L = lcnt[qi]; if (L > 16) L = 16;
      int tc = tcnt[qi]; if (tc > 16) tc = 16;
      const int need = 16 - L;
      for (int r = 0; r < need; ++r){
        int best = 0x7FFFFFFF, bj = -1;
        for (int j = 0; j < tc; ++j){
          const int v = tiebuf[qi*16+j];
          if (v < best){ best = v; bj = j; }
        }
        if (bj >= 0){ tiebuf[qi*16+bj] = 0x7FFFFFFF; orow[L+r] = best; }
        else orow[L+r] = n;
      }
    }
    return;
  }
  // ---------------- GEMM+LN path (zsel = z) ----------------
  // z=0: qa = ln(inp@WQ.T)@Wa1.T  z=1: ka = ln(inp@WK.T)@Wa1.T  z=2: lnv slice
  u16* As    = (u16*)smem;                 // 4 KB
  u16* Bs    = (u16*)(smem + 4096);        // 16 KB
  u16* lnbuf = (u16*)(smem + 20480);       // 33.8 KB
  float* sS  = (float*)(smem + 54272);
  float* sSS = (float*)(smem + 54528);
  const int z = zsel;
  const u16* wsel = wqkv + z*65536;
  const int lane = tid & 63, w = tid >> 6;
  const int mrow = lane & 15, quad = lane >> 4;
  const size_t mbase = (size_t)xb*64;
  const int wr = (w&1)*32, wc = (w>>1)*64;
  if (tid < 64){ sS[tid] = 0.f; sSS[tid] = 0.f; }
  f32x4 acc[2][4];
  #pragma unroll
  for (int i=0;i<2;++i)
    #pragma unroll
    for (int j=0;j<4;++j)
      #pragma unroll
      for (int r=0;r<4;++r) acc[i][j][r] = 0.f;
  const int sr = tid >> 2, sk = (tid & 3)*8;
  // ---- phase 1: X = inp(64 rows) @ wsel.T
  for (int k0 = 0; k0 < 256; k0 += 32){
    __syncthreads();
    if (tid < 256) async_copy16(inp + (mbase + sr)*256 + k0 + sk, &As[w*512]);
    async_copy16(wsel + (size_t)sr*256       + k0 + sk, &Bs[w*512]);
    async_copy16(wsel + (size_t)(128+sr)*256 + k0 + sk, &Bs[4096 + w*512]);
    __syncthreads();
    bf16x8 af[2], bf[4];
    #pragma unroll
    for (int rt=0;rt<2;++rt) af[rt] = *(const bf16x8*)&As[(wr+rt*16+mrow)*32 + quad*8];
    #pragma unroll
    for (int ct=0;ct<4;++ct) bf[ct] = *(const bf16x8*)&Bs[(wc+ct*16+mrow)*32 + quad*8];
    #pragma unroll
    for (int rt=0;rt<2;++rt)
      #pragma unroll
      for (int ct=0;ct<4;++ct) acc[rt][ct] = MFMA16(af[rt], bf[ct], acc[rt][ct]);
  }
  // row stats (f32) across 4 col-waves
  #pragma unroll
  for (int rt=0;rt<2;++rt)
    #pragma unroll
    for (int r=0;r<4;++r){
      float s  = acc[rt][0][r]+acc[rt][1][r]+acc[rt][2][r]+acc[rt][3][r];
      float ss = acc[rt][0][r]*acc[rt][0][r]+acc[rt][1][r]*acc[rt][1][r]
               + acc[rt][2][r]*acc[rt][2][r]+acc[rt][3][r]*acc[rt][3][r];
      s  = rowsum16(s);
      ss = rowsum16(ss);
      if (mrow == 0){
        const int row = wr + rt*16 + quad*4 + r;
        atomicAdd(&sS[row],  s);
        atomicAdd(&sSS[row], ss);
      }
    }
  __syncthreads();
  // apply LN
  #pragma unroll
  for (int ct=0;ct<4;++ct){
    const int col = wc + ct*16 + mrow;
    const float gv = g[col], bv = bta[col];
    #pragma unroll
    for (int rt=0;rt<2;++rt)
      #pragma unroll
      for (int r=0;r<4;++r){
        const int row = wr + rt*16 + quad*4 + r;
        const float mu = sS[row]*(1.f/256.f);
        const float var = sSS[row]*(1.f/256.f) - mu*mu;
        const float rs = rsqrtf(var + 1e-5f);
        const u16 hv = f2b((acc[rt][ct][r]-mu)*rs*gv + bv);
        if (z == 2) lnqkv[(mbase+row)*768 + 512 + col] = hv;
        else        lnbuf[row*LNP + col] = hv;
      }
  }
  if (z == 2) return;
  // ---- phase 2: out = lnbuf @ Wa1.T  (Bs restaged per k-step)
  u16* outp = (z == 0) ? qa : ka;
  f32x4 ac2[2][4];
  #pragma unroll
  for (int i=0;i<2;++i)
    #pragma unroll
    for (int j=0;j<4;++j)
      #pragma unroll
      for (int r=0;r<4;++r) ac2[i][j][r] = 0.f;
  for (int k0 = 0; k0 < 256; k0 += 32){
    __syncthreads();
    async_copy16(wa1 + (size_t)sr*256       + k0 + sk, &Bs[w*512]);
    async_copy16(wa1 + (size_t)(128+sr)*256 + k0 + sk, &Bs[4096 + w*512]);
    __syncthreads();
    bf16x8 af[2], bf[4];
    #pragma unroll
    for (int rt=0;rt<2;++rt) af[rt] = *(const bf16x8*)&lnbuf[(wr+rt*16+mrow)*LNP + k0 + quad*8];
    #pragma unroll
    for (int ct=0;ct<4;++ct) bf[ct] = *(const bf16x8*)&Bs[(wc+ct*16+mrow)*32 + quad*8];
    #pragma unroll
    for (int rt=0;rt<2;++rt)
      #pragma unroll
      for (int ct=0;ct<4;++ct) ac2[rt][ct] = MFMA16(af[rt], bf[ct], ac2[rt][ct]);
  }
  #pragma unroll
  for (int rt=0;rt<2;++rt)
    #pragma unroll
    for (int ct=0;ct<4;++ct){
      const size_t row0 = mbase + wr + rt*16 + quad*4;
      const int col = wc + ct*16 + mrow;
      #pragma unroll
      for (int r=0;r<4;++r) outp[(row0+r)*256 + col] = f2b(ac2[rt][ct][r]);
    }
}

// ---------------- fused: out = ln( ln(res@Wproj.T) @ Wpost.T + bpost )*g+b + feat ----------------
// 64-row tiles, 512 threads. Phase1 like gemmlnqa. Phase2: 64 cols; wave = 16 rows x 32 cols.
__global__ __launch_bounds__(512,2) void projpost_k(
    const u16* __restrict__ res, const u16* __restrict__ wproj, const u16* __restrict__ wpost,
    const float* __restrict__ bpost,
    const float* __restrict__ g_dm, const float* __restrict__ b_dm,
    const float* __restrict__ g_dp, const float* __restrict__ b_dp,
    const float* __restrict__ feat, float* __restrict__ out){
  __shared__ __attribute__((aligned(16))) u16 As[64*32];
  __shared__ __attribute__((aligned(16))) u16 Bs[256*32];
  __shared__ __attribute__((aligned(16))) u16 lnbuf[64*LNP];
  __shared__ float sS[64], sSS[64], sS2[64], sSS2[64];
  const int tid = threadIdx.x, lane = tid & 63, w = tid >> 6;
  const int mrow = lane & 15, quad = lane >> 4;
  const size_t mbase = (size_t)blockIdx.x*64;
  const int wr = (w&1)*32, wc = (w>>1)*64;
  if (tid < 64){ sS[tid]=0.f; sSS[tid]=0.f; sS2[tid]=0.f; sSS2[tid]=0.f; }
  f32x4 acc[2][4];
  #pragma unroll
  for (int i=0;i<2;++i)
    #pragma unroll
    for (int j=0;j<4;++j)
      #pragma unroll
      for (int r=0;r<4;++r) acc[i][j][r] = 0.f;
  const int sr = tid >> 2, sk = (tid & 3)*8;
  for (int k0 = 0; k0 < 256; k0 += 32){
    __syncthreads();
    if (tid < 256) async_copy16(res + (mbase + sr)*256 + k0 + sk, &As[w*512]);
    async_copy16(wproj + (size_t)sr*256       + k0 + sk, &Bs[w*512]);
    async_copy16(wproj + (size_t)(128+sr)*256 + k0 + sk, &Bs[4096 + w*512]);
    __syncthreads();
    bf16x8 af[2], bf[4];
    #pragma unroll
    for (int rt=0;rt<2;++rt) af[rt] = *(const bf16x8*)&As[(wr+rt*16+mrow)*32 + quad*8];
    #pragma unroll
    for (int ct=0;ct<4;++ct) bf[ct] = *(const bf16x8*)&Bs[(wc+ct*16+mrow)*32 + quad*8];
    #pragma unroll
    for (int rt=0;rt<2;++rt)
      #pragma unroll
      for (int ct=0;ct<4;++ct) acc[rt][ct] = MFMA16(af[rt], bf[ct], acc[rt][ct]);
  }
  #pragma unroll
  for (int rt=0;rt<2;++rt)
    #pragma unroll
    for (int r=0;r<4;++r){
      float s  = acc[rt][0][r]+acc[rt][1][r]+acc[rt][2][r]+acc[rt][3][r];
      float ss = acc[rt][0][r]*acc[rt][0][r]+acc[rt][1][r]*acc[rt][1][r]
               + acc[rt][2][r]*acc[rt][2][r]+acc[rt][3][r]*acc[rt][3][r];
      s  = rowsum16(s);
      ss = rowsum16(ss);
      if (mrow == 0){
        const int row = wr + rt*16 + quad*4 + r;
        atomicAdd(&sS[row],  s);
        atomicAdd(&sSS[row], ss);
      }
    }
  __syncthreads();
  #pragma unroll
  for (int ct=0;ct<4;++ct){
    const int col = wc + ct*16 + mrow;
    const float gv = g_dm[col], bv = b_dm[col];
    #pragma unroll
    for (int rt=0;rt<2;++rt)
      #pragma unroll
      for (int r=0;r<4;++r){
        const int row = wr + rt*16 + quad*4 + r;
        const float mu = sS[row]*(1.f/256.f);
        const float var = sSS[row]*(1.f/256.f) - mu*mu;
        const float rs = rsqrtf(var + 1e-5f);
        lnbuf[row*LNP + col] = f2b((acc[rt][ct][r]-mu)*rs*gv + bv);
      }
  }
  // ---- phase 2: d = lnbuf @ Wpost.T + bpost  (64 cols); wave = 16 rows x 32 cols
  const int wr2 = (w & 3)*16, wc2 = (w >> 2)*32;
  f32x4 ac2[2];
  #pragma unroll
  for (int j=0;j<2;++j)
    #pragma unroll
    for (int r=0;r<4;++r) ac2[j][r] = 0.f;
  for (int k0 = 0; k0 < 256; k0 += 32){
    __syncthreads();
    if (tid < 256) async_copy16(wpost + (size_t)sr*256 + k0 + sk, &Bs[w*512]);
    __syncthreads();
    bf16x8 af, bf[2];
    af = *(const bf16x8*)&lnbuf[(wr2+mrow)*LNP + k0 + quad*8];
    #pragma unroll
    for (int ct=0;ct<2;++ct) bf[ct] = *(const bf16x8*)&Bs[(wc2+ct*16+mrow)*32 + quad*8];
    #pragma unroll
    for (int ct=0;ct<2;++ct) ac2[ct] = MFMA16(af, bf[ct], ac2[ct]);
  }
  #pragma unroll
  for (int ct=0;ct<2;++ct){
    const float bv = bpost[wc2 + ct*16 + mrow];
    #pragma unroll
    for (int r=0;r<4;++r) ac2[ct][r] += bv;
  }
  #pragma unroll
  for (int r=0;r<4;++r){
    float s  = ac2[0][r] + ac2[1][r];
    float ss = ac2[0][r]*ac2[0][r] + ac2[1][r]*ac2[1][r];
    s  = rowsum16(s);
    ss = rowsum16(ss);
    if (mrow == 0){
      const int row = wr2 + quad*4 + r;
      atomicAdd(&sS2[row],  s);
      atomicAdd(&sSS2[row], ss);
    }
  }
  __syncthreads();
  #pragma unroll
  for (int ct=0;ct<2;++ct){
    const int col = wc2 + ct*16 + mrow;
    const float gv = g_dp[col], bv = b_dp[col];
    #pragma unroll
    for (int r=0;r<4;++r){
      const int row = wr2 + quad*4 + r;
      const float mu = sS2[row]*(1.f/64.f);
      const float var = sSS2[row]*(1.f/64.f) - mu*mu;
      const float rs = rsqrtf(var + 1e-5f);
      const size_t grow = mbase + row;
      out[grow*64 + col] = (ac2[ct][r]-mu)*rs*gv + bv + feat[grow*64 + col];
    }
  }
}

// ---------------- fused per-neighbor attention kernel (v18, unchanged) ----------------
#define RELP 40
// swizzled address (kept for the tid<128 prologue / reference)
__device__ __forceinline__ u16* swzp(u16* p, int row, int cb){
  return (u16*)((char*)p + row*512 + (cb ^ ((row & 7) << 4)));
}
__global__ __launch_bounds__(1024,4) void attn_k(
    const float* __restrict__ xyz, const int* __restrict__ idxb,
    const u16* __restrict__ lnqkv, const u16* __restrict__ qa, const u16* __restrict__ ka,
    const u16* __restrict__ mcomb, const u16* __restrict__ wp2, const u16* __restrict__ wa2,
    const u16* __restrict__ wp1pk, u16* __restrict__ res){
  __shared__ __attribute__((aligned(16))) u16 h1buf[128*256]; // h1, later v rows (swizzled) 64KB
  __shared__ __attribute__((aligned(16))) u16 h2buf[128*256]; // ka-gather, then h2 (swizzled) 64KB
  __shared__ __attribute__((aligned(16))) u16 qbuf[8*256];    // qa rows (LINEAR) 4KB
  __shared__ __attribute__((aligned(16))) u16 srel[128*RELP]; // 10KB
  __shared__ int sidx[128];
  const int tid = threadIdx.x;
  const int b = blockIdx.x >> 9;
  const int nbase = (blockIdx.x & 511) << 3;
  const size_t gb = (size_t)b << 12;
  if (tid < 128){
    const int m = tid;
    const int im = idxb[(gb + nbase + (m>>4))*16 + (m&15)] & 4095;
    sidx[m] = im;
    const int nn = nbase + (m>>4);
    const float* pq = xyz + (gb+nn)*3;
    const float* pm = xyz + (gb+im)*3;
    const float rx = pq[0]-pm[0], ry = pq[1]-pm[1], rz = pq[2]-pm[2];
    uint4 a; a.x = pk2f(rx,ry); a.y = pk2f(rz,0.f); a.z = 0u; a.w = 0u;
    uint4 z; z.x = z.y = z.z = z.w = 0u;
    *(uint4*)&srel[m*RELP]    = a;
    *(uint4*)&srel[m*RELP+8]  = z;
    *(uint4*)&srel[m*RELP+16] = z;
    *(uint4*)&srel[m*RELP+24] = z;
  }
  __syncthreads();
  const int lane = tid & 63, w = tid >> 6;       // w in 0..15
  const int mrow = lane & 15, quad = lane >> 4;
  const int fr = w << 4;                          // 16 f-rows per wave
  // ---- hoisted swizzled-address bases (all mt/ks terms become immediates)
  const int swc      = (mrow & 7) << 4;                   // row-XOR constant (bytes)
  const int cbst     = (2*(fr + quad*4)) ^ swc;           // C-frag col-block, swizzled
  char* h1st = (char*)h1buf + mrow*512 + cbst;            // + mt*8192 (h1 store)
  char* h2st = (char*)h2buf + mrow*512 + cbst;            // + mt*8192 (pack RMW)
  const int quadoff  = (quad*16) ^ (swc & 0x30);
  const char* h1rd = (const char*)h1buf + mrow*512 + quadoff;  // + ksx + m8*8192
  const char* h2rd = (const char*)h2buf + mrow*512 + quadoff;
  const int ksxc = swc & 0x40;
  // ---- h1 = relu(rel @ Wp1.T): wave covers h-rows [fr,fr+16) x 128 pairs
  {
    bf16x8 aW = *(const bf16x8*)&wp1pk[(fr+mrow)*32 + quad*8];
    #pragma unroll
    for (int mt=0;mt<8;++mt){
      bf16x8 bR = *(const bf16x8*)&srel[(mt*16+mrow)*RELP + quad*8];
      f32x4 hz;
      #pragma unroll
      for (int r=0;r<4;++r) hz[r]=0.f;
      hz = MFMA16(aW, bR, hz);
      float h0 = hz[0]>0.f?hz[0]:0.f, h1v = hz[1]>0.f?hz[1]:0.f;
      float h2v = hz[2]>0.f?hz[2]:0.f, h3 = hz[3]>0.f?hz[3]:0.f;
      uint2 o; o.x = pk2f(h0,h1v); o.y = pk2f(h2v,h3);
      *(uint2*)(h1st + mt*8192) = o;
    }
  }
  __syncthreads();
  // ---- pre-gather: ka rows -> h2buf (all waves), qa rows -> qbuf (waves 0..3, linear).
  // Issued before loop1; the barrier after loop1 drains them (vmcnt(0)).
  {
    #pragma unroll
    for (int i = 0; i < 4; ++i){
      const int row = w*8 + i*2 + (lane>>5);
      const int c   = ((lane&31)*8) ^ ((row & 7) << 3);   // u16 elems, inverse swizzle
      async_copy16(ka + (gb + (size_t)sidx[row])*256 + c,
                   &h2buf[w*2048 + i*512]);
    }
    if (w < 4){
      const int row = w*2 + (lane>>5);
      async_copy16(qa + (gb + nbase + row)*256 + (lane&31)*8, &qbuf[w*512]);
    }
  }
  // ---- loop1: at = mcomb @ h1 ; av = h1 @ wp2.T  (K = 256 over h)
  f32x4 at[8], av[8];
  #pragma unroll
  for (int j=0;j<8;++j)
    #pragma unroll
    for (int r=0;r<4;++r){ at[j][r]=0.f; av[j][r]=0.f; }
  #pragma unroll 1
  for (int ks = 0; ks < 8; ++ks){
    const int koff = ks*32 + quad*8;
    bf16x8 aM = *(const bf16x8*)&mcomb[(fr+mrow)*256 + koff];
    bf16x8 aP = *(const bf16x8*)&wp2  [(fr+mrow)*256 + koff];
    const char* hb = h1rd + ((ks*64) ^ ksxc);
    #pragma unroll
    for (int mh=0; mh<2; ++mh){
      bf16x8 bH[4];
      #pragma unroll
      for (int mi=0;mi<4;++mi) bH[mi] = *(const bf16x8*)(hb + (mh*4+mi)*8192);
      #pragma unroll
      for (int mi=0;mi<4;++mi){
        at[mh*4+mi] = MFMA16(aM, bH[mi], at[mh*4+mi]);
        av[mh*4+mi] = MFMA16(bH[mi], aP, av[mh*4+mi]);
      }
    }
  }
  __syncthreads();   // drains ka/qa gathers; h2buf(ka)+qbuf now visible to all
  // ---- pack: h2 = relu(at + qa - ka) -> bf16 (swizzled, overwrites ka in place)
  #pragma unroll
  for (int mt=0;mt<8;++mt){
    u16* addr = (u16*)(h2st + mt*8192);
    const uint2 kv = *(const uint2*)addr;
    const uint2 qv = *(const uint2*)&qbuf[mt*256 + fr + quad*4];
    float t0 = at[mt][0] + b2f(qv.x&0xffff) - b2f(kv.x&0xffff);
    float t1 = at[mt][1] + b2f(qv.x>>16)    - b2f(kv.x>>16);
    float t2 = at[mt][2] + b2f(qv.y&0xffff) - b2f(kv.y&0xffff);
    float t3 = at[mt][3] + b2f(qv.y>>16)    - b2f(kv.y>>16);
    t0 = t0>0.f?t0:0.f; t1 = t1>0.f?t1:0.f; t2 = t2>0.f?t2:0.f; t3 = t3>0.f?t3:0.f;
    uint2 o; o.x = pk2f(t0,t1); o.y = pk2f(t2,t3);
    *(uint2*)addr = o;
  }
  __syncthreads();
  // ---- async v-gather: linear LDS dest, inverse-swizzled global source (hidden under loop2)
  {
    #pragma unroll
    for (int i = 0; i < 4; ++i){
      const int row = w*8 + i*2 + (lane>>5);
      const int c   = ((lane&31)*8) ^ ((row & 7) << 3);
      async_copy16(lnqkv + (gb + (size_t)sidx[row])*768 + 512 + c,
                   &h1buf[w*2048 + i*512]);
    }
  }
  // ---- loop2: al = h2 @ wa2.T
  f32x4 al[8];
  #pragma unroll
  for (int j=0;j<8;++j)
    #pragma unroll
    for (int r=0;r<4;++r) al[j][r]=0.f;
  #pragma unroll 1
  for (int ks = 0; ks < 8; ++ks){
    const int koff = ks*32 + quad*8;
    bf16x8 aW = *(const bf16x8*)&wa2[(fr+mrow)*256 + koff];
    const char* hb = h2rd + ((ks*64) ^ ksxc);
    #pragma unroll
    for (int mh=0; mh<2; ++mh){
      bf16x8 bH[4];
      #pragma unroll
      for (int mi=0;mi<4;++mi) bH[mi] = *(const bf16x8*)(hb + (mh*4+mi)*8192);
      #pragma unroll
      for (int mi=0;mi<4;++mi) al[mh*4+mi] = MFMA16(bH[mi], aW, al[mh*4+mi]);
    }
  }
  __syncthreads();
  // ---- softmax over the 16 neighbors + weighted reduce of (v + pos)
  const float sc = 0.0901684f;   // log2(e)/sqrt(256)
  // hoisted v-read bases: addr(mt,r) = vb_r + mt*8192 (imm)
  const char* vb0 = (const char*)h1buf + (quad*4+0)*512 + ((2*(fr+mrow)) ^ ((((quad*4)+0)&7)<<4));
  const char* vb1 = (const char*)h1buf + (quad*4+1)*512 + ((2*(fr+mrow)) ^ ((((quad*4)+1)&7)<<4));
  const char* vb2 = (const char*)h1buf + (quad*4+2)*512 + ((2*(fr+mrow)) ^ ((((quad*4)+2)&7)<<4));
  const char* vb3 = (const char*)h1buf + (quad*4+3)*512 + ((2*(fr+mrow)) ^ ((((quad*4)+3)&7)<<4));
  #pragma unroll
  for (int mt=0;mt<8;++mt){
    float prs = 0.f, wgs = 0.f;
    {
      const float val = av[mt][0] + b2f(*(const u16*)(vb0 + mt*8192));
      const float pr = exp2f(al[mt][0]*sc); prs += pr; wgs += pr*val;
    }
    {
      const float val = av[mt][1] + b2f(*(const u16*)(vb1 + mt*8192));
      const float pr = exp2f(al[mt][1]*sc); prs += pr; wgs += pr*val;
    }
    {
      const float val = av[mt][2] + b2f(*(const u16*)(vb2 + mt*8192));
      const float pr = exp2f(al[mt][2]*sc); prs += pr; wgs += pr*val;
    }
    {
      const float val = av[mt][3] + b2f(*(const u16*)(vb3 + mt*8192));
      const float pr = exp2f(al[mt][3]*sc); prs += pr; wgs += pr*val;
    }
    prs += __shfl_xor(prs, 16, 64); prs += __shfl_xor(prs, 32, 64);
    wgs += __shfl_xor(wgs, 16, 64); wgs += __shfl_xor(wgs, 32, 64);
    const float rv = wgs * __builtin_amdgcn_rcpf(prs);
    if (quad == 0)
      res[(gb + nbase + mt)*256 + fr + mrow] = f2b(rv);
  }
}

// ---------------- launcher ----------------
extern "C" void kernel_launch(void* const* d_in, const int* in_sizes, int n_in,
                              void* d_out, int out_size, void* d_ws, size_t ws_size,
                              hipStream_t stream){
  const float* xyz    = (const float*)d_in[0];
  const float* feat   = (const float*)d_in[1];
  const float* W_pre  = (const float*)d_in[2];
  const float* b_pre  = (const float*)d_in[3];
  const float* W_post = (const float*)d_in[4];
  const float* b_post = (const float*)d_in[5];
  const float* Wp1    = (const float*)d_in[6];
  const float* Wp2    = (const float*)d_in[7];
  const float* Wa1    = (const float*)d_in[8];
  const float* Wa2    = (const float*)d_in[9];
  const float* WQ     = (const float*)d_in[10];
  const float* WK     = (const float*)d_in[11];
  const float* WV     = (const float*)d_in[12];
  const float* Wproj  = (const float*)d_in[13];
  const float* g_dm   = (const float*)d_in[14];
  const float* b_dm   = (const float*)d_in[15];
  const float* g_dp   = (const float*)d_in[16];
  const float* b_dp   = (const float*)d_in[17];
  float* out = (float*)d_out;
  if (ws_size < WS_NEED) return;
  char* ws = (char*)d_ws;
  int* idxw   = (int*)(ws + OFF_IDX);
  u16* wqkvb  = (u16*)(ws + OFF_WQKV);
  u16* wa1b   = (u16*)(ws + OFF_WA1);
  u16* wa2b   = (u16*)(ws + OFF_WA2);
  u16* wp2b   = (u16*)(ws + OFF_WP2);
  u16* wprojb = (u16*)(ws + OFF_WPROJ);
  u16* wpostb = (u16*)(ws + OFF_WPOST);
  u16* mcombb = (u16*)(ws + OFF_MCOMB);
  u16* inp    = (u16*)(ws + OFF_INP);
  u16* lnqkv  = (u16*)(ws + OFF_LNQKV);
  u16* qab    = (u16*)(ws + OFF_QA);
  u16* kab    = (u16*)(ws + OFF_KA);
  u16* resb   = (u16*)(ws + OFF_RES);
  u16* wp1pk  = (u16*)(ws + OFF_WP1PK);

  // 1) weight converts + wp1 pack + mcomb + inp GEMM
  prep_w_k<<<2369,256,0,stream>>>(feat, W_pre, b_pre, WQ, WK, WV, Wa1, Wa2, Wp2,
                                  Wproj, W_post, Wp1,
                                  wqkvb, wa1b, wa2b, wp2b, wprojb, wpostb,
                                  wp1pk, mcombb, inp);
  // 2) merged: gemm+LN (z=0..2) co-scheduled with kNN (z=3..6); x-fastest
  //    dispatch interleaves 3 gemm + 4 knn blocks per group.
  gemmknn_k<<<dim3(7,1,256),512,0,stream>>>(inp, wqkvb, wa1b, qab, kab, lnqkv,
                                            g_dm, b_dm, xyz, idxw);
  // 3) attention: 2048 blocks x 1024 threads, 8 queries/block
  attn_k<<<2048,1024,0,stream>>>(xyz,idxw,lnqkv,qab,kab,mcombb,wp2b,wa2b,wp1pk,resb);
  // 4) out = ln( ln(res@Wproj.T)@Wpost.T + b_post )*g+b + feat
  projpost_k<<<256,512,0,stream>>>(resb, wprojb, wpostb, b_post, g_dm, b_dm, g_dp, b_dp,
                                   feat, out);
}

// Round 11
// 390.547 us; speedup vs baseline: 1.0799x; 1.0799x over previous
//
#include <hip/hip_runtime.h>
#include <hip/hip_bf16.h>

typedef unsigned short u16;
typedef unsigned int   u32;
typedef __attribute__((ext_vector_type(8))) short bf16x8;
typedef __attribute__((ext_vector_type(4))) float f32x4;

#define MFMA16(a,b,c) __builtin_amdgcn_mfma_f32_16x16x32_bf16((a),(b),(c),0,0,0)

__device__ __forceinline__ float b2f(u32 h){ return __uint_as_float(h<<16); }
__device__ __forceinline__ u16 f2b(float f){
  u32 u = __float_as_uint(f);
  return (u16)((u + 0x7FFFu + ((u>>16)&1u))>>16);
}
// HW packed convert: v_cvt_pk_bf16_f32 (RNE)
__device__ __forceinline__ u32 pk2f(float a,float b){
  __hip_bfloat162 h = __float22bfloat162_rn(float2{a,b});
  return *reinterpret_cast<u32*>(&h);
}
__device__ __forceinline__ u32 umin32(u32 a,u32 b){ return a<b?a:b; }
__device__ __forceinline__ u32 umax32(u32 a,u32 b){ return a>b?a:b; }

// 16-lane row-sum on the VALU pipe via DPP row_ror
template<int CTRL>
__device__ __forceinline__ float dpp_add(float x){
  int t = __builtin_amdgcn_update_dpp(0, __float_as_int(x), CTRL, 0xF, 0xF, true);
  return x + __int_as_float(t);
}
__device__ __forceinline__ float rowsum16(float x){
  x = dpp_add<0x121>(x);
  x = dpp_add<0x122>(x);
  x = dpp_add<0x124>(x);
  x = dpp_add<0x128>(x);
  return x;
}

__device__ __forceinline__ void async_copy16(const void* g, void* l){
  __builtin_amdgcn_global_load_lds((const __attribute__((address_space(1))) u32*)g,
                                   (__attribute__((address_space(3))) u32*)l, 16, 0, 0);
}

// ---------------- workspace layout (bytes) ----------------
#define OFF_IDX    0ull
#define OFF_WQKV   3178496ull
#define OFF_WA1    3571712ull
#define OFF_WA2    3702784ull
#define OFF_WP2    3833856ull
#define OFF_WPROJ  3964928ull
#define OFF_WPOST  4096000ull
#define OFF_MCOMB  4128768ull
#define OFF_INP    4259840ull
#define OFF_LNQKV  37814272ull
#define OFF_QA     62980096ull
#define OFF_KA     71368704ull
#define OFF_RES    79757312ull
#define OFF_D1     88145920ull
#define WS_NEED    104923136ull
#define OFF_WP1PK  OFF_D1

// ---------------- kNN insertion: a[j] = med3(a[j-1], key, a[j]) ----------------
// Given sorted a[0..15] ascending, min(max(a[j-1],key),a[j]) == median3 of the
// three. v_med3_u32 replaces the 2-op min/max pair -> 16 instr per candidate.
__device__ __forceinline__ void ins16(u32 (&a)[16], u32 key){
  #pragma unroll
  for (int j = 15; j >= 1; --j){
    u32 r;
    asm("v_med3_u32 %0, %1, %2, %3" : "=v"(r) : "v"(a[j-1]), "v"(key), "v"(a[j]));
    a[j] = r;
  }
  a[0] = umin32(a[0], key);
}

__device__ __forceinline__ float dist2(float ax,float ay,float az,float bx,float by,float bz){
  const float dx = ax-bx, dy = ay-by, dz = az-bz;
  return __fmaf_rn(dx,dx, __fmaf_rn(dy,dy, dz*dz));
}

// ---------------- prep (weights): converts + wp1 pack + mcomb + inp GEMM ----------------
__global__ __launch_bounds__(256,2) void prep_w_k(
    const float* __restrict__ feat,
    const float* __restrict__ wpre, const float* __restrict__ bpre,
    const float* __restrict__ wq, const float* __restrict__ wk, const float* __restrict__ wv,
    const float* __restrict__ wa1, const float* __restrict__ wa2, const float* __restrict__ wp2,
    const float* __restrict__ wproj, const float* __restrict__ wpost,
    const float* __restrict__ wp1,
    u16* __restrict__ dwqkv, u16* __restrict__ dwa1, u16* __restrict__ dwa2,
    u16* __restrict__ dwp2, u16* __restrict__ dwproj, u16* __restrict__ dwpost,
    u16* __restrict__ dwp1pk, u16* __restrict__ dmcomb,
    u16* __restrict__ dinp){
  __shared__ __attribute__((aligned(16))) char smem[36864];
  const int bid = blockIdx.x, tid = threadIdx.x;
  if (bid < 1856){
    int id = bid*256 + tid;
    const float* s; u16* d; int off;
    if      (id <  65536){ s=wq;    d=dwqkv;        off=id; }
    else if (id < 131072){ s=wk;    d=dwqkv+65536;  off=id-65536; }
    else if (id < 196608){ s=wv;    d=dwqkv+131072; off=id-131072; }
    else if (id < 262144){ s=wa1;   d=dwa1;         off=id-196608; }
    else if (id < 327680){ s=wa2;   d=dwa2;         off=id-262144; }
    else if (id < 393216){ s=wp2;   d=dwp2;         off=id-327680; }
    else if (id < 458752){ s=wproj; d=dwproj;       off=id-393216; }
    else                 { s=wpost; d=dwpost;       off=id-458752; }
    d[off] = f2b(s[off]);
  } else if (bid == 1856){
    const int h = tid;
    const float w0 = wp1[h*3], w1 = wp1[h*3+1], w2 = wp1[h*3+2];
    uint4 a; a.x = pk2f(w0,w1); a.y = pk2f(w2,0.f); a.z = 0u; a.w = 0u;
    uint4 z; z.x = z.y = z.z = z.w = 0u;
    *(uint4*)&dwp1pk[h*32]    = a;
    *(uint4*)&dwp1pk[h*32+8]  = z;
    *(uint4*)&dwp1pk[h*32+16] = z;
    *(uint4*)&dwp1pk[h*32+24] = z;
  } else if (bid < 2113){
    const int f = bid - 1857, h = tid;
    float acc = 0.f;
    #pragma unroll 4
    for (int j = 0; j < 256; ++j) acc = __fmaf_rn(wa1[f*256+j], wp2[j*256+h], acc);
    dmcomb[f*256+h] = f2b(acc);
  } else {
    // ---- inp = feat @ W_pre.T + b_pre (K=64), 128x128 tile
    u16* As = (u16*)smem;            // [128][72]
    u16* Bs = (u16*)smem + 9216;     // [128][72]
    const int tb = bid - 2113;
    const int mb = tb >> 1, nb = tb & 1;
    #pragma unroll
    for (int i = 0; i < 32; ++i){
      const int e = i*256 + tid;
      const int row = e >> 6, k = e & 63;
      As[row*72+k] = f2b(feat[(size_t)(mb*128)*64 + e]);
      Bs[row*72+k] = f2b(wpre[(size_t)(nb*128)*64 + e]);
    }
    __syncthreads();
    const int lane = tid & 63, w = tid >> 6;
    const int mrow = lane & 15, quad = lane >> 4;
    const int wr = (w&1)*64, wc = (w>>1)*64;
    f32x4 acc[4][4];
    #pragma unroll
    for (int i=0;i<4;++i)
      #pragma unroll
      for (int j=0;j<4;++j)
        #pragma unroll
        for (int r=0;r<4;++r) acc[i][j][r] = 0.f;
    #pragma unroll
    for (int ks = 0; ks < 2; ++ks){
      const int koff = ks*32 + quad*8;
      bf16x8 af[4], bf[4];
      #pragma unroll
      for (int rt=0;rt<4;++rt) af[rt] = *(const bf16x8*)&As[(wr+rt*16+mrow)*72 + koff];
      #pragma unroll
      for (int ct=0;ct<4;++ct) bf[ct] = *(const bf16x8*)&Bs[(wc+ct*16+mrow)*72 + koff];
      #pragma unroll
      for (int rt=0;rt<4;++rt)
        #pragma unroll
        for (int ct=0;ct<4;++ct) acc[rt][ct] = MFMA16(af[rt], bf[ct], acc[rt][ct]);
    }
    #pragma unroll
    for (int rt=0;rt<4;++rt)
      #pragma unroll
      for (int ct=0;ct<4;++ct){
        const size_t row0 = (size_t)mb*128 + wr + rt*16 + quad*4;
        const int col = nb*128 + wc + ct*16 + mrow;
        const float bv = bpre[col];
        #pragma unroll
        for (int r=0;r<4;++r) dinp[(row0+r)*256 + col] = f2b(acc[rt][ct][r] + bv);
      }
  }
}

// ---------------- kNN kernel ----------------
// v2 (round-9 winner) + launch_bounds(256,3): LDS 50.4KB allows 3 blocks/CU
// (151KB < 160KB) and ~60 VGPR fits 3 waves/EU -> +50% resident waves vs (256,2).
__global__ __launch_bounds__(256,3) void knn_k(
    const float* __restrict__ xyz, int* __restrict__ idxout){
  __shared__ __attribute__((aligned(16))) char smem[51200];
  float* sx = (float*)smem;              // [16][260]
  float* sy = sx + 4160;
  float* sz = sy + 4160;                 // ends at byte 49920
  int* lcnt   = (int*)(smem + 49920);
  int* tcnt   = (int*)(smem + 49984);
  u32* tbuf   = (u32*)(smem + 50048);
  int* tiebuf = (int*)(smem + 50112);    // 1024 B -> 51136
  const int bid = blockIdx.x, tid = threadIdx.x;
  const int b  = bid >> 8;
  const int n0 = (bid & 255) << 4;
  const float* base = xyz + (size_t)b*12288;
  #pragma unroll
  for (int i = 0; i < 12; ++i){
    const float4 v = *(const float4*)(base + tid*48 + i*4);
    const float vv[4] = {v.x, v.y, v.z, v.w};
    #pragma unroll
    for (int j = 0; j < 4; ++j){
      const int e = i*4 + j;
      const int c = e % 3;
      const int m = tid*16 + e/3;
      float* arr = (c==0)?sx:((c==1)?sy:sz);
      arr[(m>>8)*260 + (m&255)] = vv[j];
    }
  }
  if (tid < 16){ lcnt[tid] = 0; tcnt[tid] = 0; }
  __syncthreads();
  const int qi = tid >> 4, p = tid & 15;
  const int n = n0 + qi;
  const float qx = sx[(n>>8)*260 + (n&255)];
  const float qy = sy[(n>>8)*260 + (n&255)];
  const float qz = sz[(n>>8)*260 + (n&255)];
  u32 a[16];
  #pragma unroll
  for (int j = 0; j < 16; ++j) a[j] = 0xFFFFFFFFu;
  const float* px = sx + p*260;
  const float* py = sy + p*260;
  const float* pz = sz + p*260;
  #pragma unroll 2
  for (int i4 = 0; i4 < 64; ++i4){
    const float4 x4 = *(const float4*)(px + i4*4);
    const float4 y4 = *(const float4*)(py + i4*4);
    const float4 z4 = *(const float4*)(pz + i4*4);
    ins16(a, __float_as_uint(dist2(x4.x,y4.x,z4.x,qx,qy,qz)));
    ins16(a, __float_as_uint(dist2(x4.y,y4.y,z4.y,qx,qy,qz)));
    ins16(a, __float_as_uint(dist2(x4.z,y4.z,z4.z,qx,qy,qz)));
    ins16(a, __float_as_uint(dist2(x4.w,y4.w,z4.w,qx,qy,qz)));
  }
  #pragma unroll
  for (int s = 8; s >= 1; s >>= 1){
    u32 o[16];
    #pragma unroll
    for (int j = 0; j < 16; ++j) o[j] = __shfl_down(a[j], (unsigned)s, 64);
    if (p < s){
      #pragma unroll
      for (int j = 0; j < 16; ++j) ins16(a, o[j]);
    }
  }
  if (p == 0) tbuf[qi] = a[15];
  __syncthreads();
  const u32 T = tbuf[qi];
  int* orow = idxout + ((size_t)(b<<12)+n)*16;
  const int gbase = p*256;
  for (int i4 = 0; i4 < 64; ++i4){
    const float4 x4 = *(const float4*)(px + i4*4);
    const float4 y4 = *(const float4*)(py + i4*4);
    const float4 z4 = *(const float4*)(pz + i4*4);
    const float xv[4] = {x4.x,x4.y,x4.z,x4.w};
    const float yv[4] = {y4.x,y4.y,y4.z,y4.w};
    const float zv[4] = {z4.x,z4.y,z4.z,z4.w};
    #pragma unroll
    for (int j = 0; j < 4; ++j){
      const float d2 = dist2(xv[j],yv[j],zv[j],qx,qy,qz);
      const u32 kb = __float_as_uint(d2);
      if (kb < T){
        const int pos = atomicAdd(&lcnt[qi],1);
        if (pos < 16) orow[pos] = gbase + i4*4 + j;
      } else if (kb == T){
        const int t = atomicAdd(&tcnt[qi],1);
        if (t < 16) tiebuf[qi*16+t] = gbase + i4*4 + j;
      }
    }
  }
  __syncthreads();
  if (p == 0){
    int L = lcnt[qi]; if (L > 16) L = 16;
    int tc = tcnt[qi]; if (tc > 16) tc = 16;
    const int need = 16 - L;
    for (int r = 0; r < need; ++r){
      int best = 0x7FFFFFFF, bj = -1;
      for (int j = 0; j < tc; ++j){
        const int v = tiebuf[qi*16+j];
        if (v < best){ best = v; bj = j; }
      }
      if (bj >= 0){ tiebuf[qi*16+bj] = 0x7FFFFFFF; orow[L+r] = best; }
      else orow[L+r] = n;
    }
  }
}

// ---------------- fused GEMM+LN (+second GEMM for qa/ka): 64-row tiles ----------------
// z=0: qa = ln(inp@WQ.T) @ Wa1.T   z=1: ka = ln(inp@WK.T) @ Wa1.T
// z=2: lnv slice = ln(inp@WV.T)  (written to lnqkv[...,512:768])
// 512 threads = 8 waves. Phase1 wave: rows (w&1)*32..+32, cols (w>>1)*64..+64.
#define LNP 264
__global__ __launch_bounds__(512,2) void gemmlnqa_k(
    const u16* __restrict__ inp, const u16* __restrict__ wqkv, const u16* __restrict__ wa1,
    u16* __restrict__ qa, u16* __restrict__ ka, u16* __restrict__ lnqkv,
    const float* __restrict__ g, const float* __restrict__ bta){
  __shared__ __attribute__((aligned(16))) u16 As[64*32];      // 4 KB
  __shared__ __attribute__((aligned(16))) u16 Bs[256*32];     // 16 KB
  __shared__ __attribute__((aligned(16))) u16 lnbuf[64*LNP];  // 33.8 KB
  __shared__ float sS[64], sSS[64];
  const int z = blockIdx.z;
  const u16* wsel = wqkv + z*65536;
  const int tid = threadIdx.x, lane = tid & 63, w = tid >> 6;
  const int mrow = lane & 15, quad = lane >> 4;
  const size_t mbase = (size_t)blockIdx.x*64;
  const int wr = (w&1)*32, wc = (w>>1)*64;
  if (tid < 64){ sS[tid] = 0.f; sSS[tid] = 0.f; }
  f32x4 acc[2][4];
  #pragma unroll
  for (int i=0;i<2;++i)
    #pragma unroll
    for (int j=0;j<4;++j)
      #pragma unroll
      for (int r=0;r<4;++r) acc[i][j][r] = 0.f;
  const int sr = tid >> 2, sk = (tid & 3)*8;
  // ---- phase 1: X = inp(64 rows) @ wsel.T
  for (int k0 = 0; k0 < 256; k0 += 32){
    __syncthreads();
    if (tid < 256) async_copy16(inp + (mbase + sr)*256 + k0 + sk, &As[w*512]);
    async_copy16(wsel + (size_t)sr*256       + k0 + sk, &Bs[w*512]);
    async_copy16(wsel + (size_t)(128+sr)*256 + k0 + sk, &Bs[4096 + w*512]);
    __syncthreads();
    bf16x8 af[2], bf[4];
    #pragma unroll
    for (int rt=0;rt<2;++rt) af[rt] = *(const bf16x8*)&As[(wr+rt*16+mrow)*32 + quad*8];
    #pragma unroll
    for (int ct=0;ct<4;++ct) bf[ct] = *(const bf16x8*)&Bs[(wc+ct*16+mrow)*32 + quad*8];
    #pragma unroll
    for (int rt=0;rt<2;++rt)
      #pragma unroll
      for (int ct=0;ct<4;++ct) acc[rt][ct] = MFMA16(af[rt], bf[ct], acc[rt][ct]);
  }
  // row stats (f32) across 4 col-waves
  #pragma unroll
  for (int rt=0;rt<2;++rt)
    #pragma unroll
    for (int r=0;r<4;++r){
      float s  = acc[rt][0][r]+acc[rt][1][r]+acc[rt][2][r]+acc[rt][3][r];
      float ss = acc[rt][0][r]*acc[rt][0][r]+acc[rt][1][r]*acc[rt][1][r]
               + acc[rt][2][r]*acc[rt][2][r]+acc[rt][3][r]*acc[rt][3][r];
      s  = rowsum16(s);
      ss = rowsum16(ss);
      if (mrow == 0){
        const int row = wr + rt*16 + quad*4 + r;
        atomicAdd(&sS[row],  s);
        atomicAdd(&sSS[row], ss);
      }
    }
  __syncthreads();
  // apply LN
  #pragma unroll
  for (int ct=0;ct<4;++ct){
    const int col = wc + ct*16 + mrow;
    const float gv = g[col], bv = bta[col];
    #pragma unroll
    for (int rt=0;rt<2;++rt)
      #pragma unroll
      for (int r=0;r<4;++r){
        const int row = wr + rt*16 + quad*4 + r;
        const float mu = sS[row]*(1.f/256.f);
        const float var = sSS[row]*(1.f/256.f) - mu*mu;
        const float rs = rsqrtf(var + 1e-5f);
        const u16 hv = f2b((acc[rt][ct][r]-mu)*rs*gv + bv);
        if (z == 2) lnqkv[(mbase+row)*768 + 512 + col] = hv;
        else        lnbuf[row*LNP + col] = hv;
      }
  }
  if (z == 2) return;
  // ---- phase 2: out = lnbuf @ Wa1.T  (Bs restaged per k-step)
  u16* outp = (z == 0) ? qa : ka;
  f32x4 ac2[2][4];
  #pragma unroll
  for (int i=0;i<2;++i)
    #pragma unroll
    for (int j=0;j<4;++j)
      #pragma unroll
      for (int r=0;r<4;++r) ac2[i][j][r] = 0.f;
  for (int k0 = 0; k0 < 256; k0 += 32){
    __syncthreads();
    async_copy16(wa1 + (size_t)sr*256       + k0 + sk, &Bs[w*512]);
    async_copy16(wa1 + (size_t)(128+sr)*256 + k0 + sk, &Bs[4096 + w*512]);
    __syncthreads();
    bf16x8 af[2], bf[4];
    #pragma unroll
    for (int rt=0;rt<2;++rt) af[rt] = *(const bf16x8*)&lnbuf[(wr+rt*16+mrow)*LNP + k0 + quad*8];
    #pragma unroll
    for (int ct=0;ct<4;++ct) bf[ct] = *(const bf16x8*)&Bs[(wc+ct*16+mrow)*32 + quad*8];
    #pragma unroll
    for (int rt=0;rt<2;++rt)
      #pragma unroll
      for (int ct=0;ct<4;++ct) ac2[rt][ct] = MFMA16(af[rt], bf[ct], ac2[rt][ct]);
  }
  #pragma unroll
  for (int rt=0;rt<2;++rt)
    #pragma unroll
    for (int ct=0;ct<4;++ct){
      const size_t row0 = mbase + wr + rt*16 + quad*4;
      const int col = wc + ct*16 + mrow;
      #pragma unroll
      for (int r=0;r<4;++r) outp[(row0+r)*256 + col] = f2b(ac2[rt][ct][r]);
    }
}

// ---------------- fused: out = ln( ln(res@Wproj.T) @ Wpost.T + bpost )*g+b + feat ----------------
// 64-row tiles, 512 threads. Phase1 like gemmlnqa. Phase2: 64 cols; wave = 16 rows x 32 cols.
__global__ __launch_bounds__(512,2) void projpost_k(
    const u16* __restrict__ res, const u16* __restrict__ wproj, const u16* __restrict__ wpost,
    const float* __restrict__ bpost,
    const float* __restrict__ g_dm, const float* __restrict__ b_dm,
    const float* __restrict__ g_dp, const float* __restrict__ b_dp,
    const float* __restrict__ feat, float* __restrict__ out){
  __shared__ __attribute__((aligned(16))) u16 As[64*32];
  __shared__ __attribute__((aligned(16))) u16 Bs[256*32];
  __shared__ __attribute__((aligned(16))) u16 lnbuf[64*LNP];
  __shared__ float sS[64], sSS[64], sS2[64], sSS2[64];
  const int tid = threadIdx.x, lane = tid & 63, w = tid >> 6;
  const int mrow = lane & 15, quad = lane >> 4;
  const size_t mbase = (size_t)blockIdx.x*64;
  const int wr = (w&1)*32, wc = (w>>1)*64;
  if (tid < 64){ sS[tid]=0.f; sSS[tid]=0.f; sS2[tid]=0.f; sSS2[tid]=0.f; }
  f32x4 acc[2][4];
  #pragma unroll
  for (int i=0;i<2;++i)
    #pragma unroll
    for (int j=0;j<4;++j)
      #pragma unroll
      for (int r=0;r<4;++r) acc[i][j][r] = 0.f;
  const int sr = tid >> 2, sk = (tid & 3)*8;
  for (int k0 = 0; k0 < 256; k0 += 32){
    __syncthreads();
    if (tid < 256) async_copy16(res + (mbase + sr)*256 + k0 + sk, &As[w*512]);
    async_copy16(wproj + (size_t)sr*256       + k0 + sk, &Bs[w*512]);
    async_copy16(wproj + (size_t)(128+sr)*256 + k0 + sk, &Bs[4096 + w*512]);
    __syncthreads();
    bf16x8 af[2], bf[4];
    #pragma unroll
    for (int rt=0;rt<2;++rt) af[rt] = *(const bf16x8*)&As[(wr+rt*16+mrow)*32 + quad*8];
    #pragma unroll
    for (int ct=0;ct<4;++ct) bf[ct] = *(const bf16x8*)&Bs[(wc+ct*16+mrow)*32 + quad*8];
    #pragma unroll
    for (int rt=0;rt<2;++rt)
      #pragma unroll
      for (int ct=0;ct<4;++ct) acc[rt][ct] = MFMA16(af[rt], bf[ct], acc[rt][ct]);
  }
  #pragma unroll
  for (int rt=0;rt<2;++rt)
    #pragma unroll
    for (int r=0;r<4;++r){
      float s  = acc[rt][0][r]+acc[rt][1][r]+acc[rt][2][r]+acc[rt][3][r];
      float ss = acc[rt][0][r]*acc[rt][0][r]+acc[rt][1][r]*acc[rt][1][r]
               + acc[rt][2][r]*acc[rt][2][r]+acc[rt][3][r]*acc[rt][3][r];
      s  = rowsum16(s);
      ss = rowsum16(ss);
      if (mrow == 0){
        const int row = wr + rt*16 + quad*4 + r;
        atomicAdd(&sS[row],  s);
        atomicAdd(&sSS[row], ss);
      }
    }
  __syncthreads();
  #pragma unroll
  for (int ct=0;ct<4;++ct){
    const int col = wc + ct*16 + mrow;
    const float gv = g_dm[col], bv = b_dm[col];
    #pragma unroll
    for (int rt=0;rt<2;++rt)
      #pragma unroll
      for (int r=0;r<4;++r){
        const int row = wr + rt*16 + quad*4 + r;
        const float mu = sS[row]*(1.f/256.f);
        const float var = sSS[row]*(1.f/256.f) - mu*mu;
        const float rs = rsqrtf(var + 1e-5f);
        lnbuf[row*LNP + col] = f2b((acc[rt][ct][r]-mu)*rs*gv + bv);
      }
  }
  // ---- phase 2: d = lnbuf @ Wpost.T + bpost  (64 cols); wave = 16 rows x 32 cols
  const int wr2 = (w & 3)*16, wc2 = (w >> 2)*32;
  f32x4 ac2[2];
  #pragma unroll
  for (int j=0;j<2;++j)
    #pragma unroll
    for (int r=0;r<4;++r) ac2[j][r] = 0.f;
  for (int k0 = 0; k0 < 256; k0 += 32){
    __syncthreads();
    if (tid < 256) async_copy16(wpost + (size_t)sr*256 + k0 + sk, &Bs[w*512]);
    __syncthreads();
    bf16x8 af, bf[2];
    af = *(const bf16x8*)&lnbuf[(wr2+mrow)*LNP + k0 + quad*8];
    #pragma unroll
    for (int ct=0;ct<2;++ct) bf[ct] = *(const bf16x8*)&Bs[(wc2+ct*16+mrow)*32 + quad*8];
    #pragma unroll
    for (int ct=0;ct<2;++ct) ac2[ct] = MFMA16(af, bf[ct], ac2[ct]);
  }
  #pragma unroll
  for (int ct=0;ct<2;++ct){
    const float bv = bpost[wc2 + ct*16 + mrow];
    #pragma unroll
    for (int r=0;r<4;++r) ac2[ct][r] += bv;
  }
  #pragma unroll
  for (int r=0;r<4;++r){
    float s  = ac2[0][r] + ac2[1][r];
    float ss = ac2[0][r]*ac2[0][r] + ac2[1][r]*ac2[1][r];
    s  = rowsum16(s);
    ss = rowsum16(ss);
    if (mrow == 0){
      const int row = wr2 + quad*4 + r;
      atomicAdd(&sS2[row],  s);
      atomicAdd(&sSS2[row], ss);
    }
  }
  __syncthreads();
  #pragma unroll
  for (int ct=0;ct<2;++ct){
    const int col = wc2 + ct*16 + mrow;
    const float gv = g_dp[col], bv = b_dp[col];
    #pragma unroll
    for (int r=0;r<4;++r){
      const int row = wr2 + quad*4 + r;
      const float mu = sS2[row]*(1.f/64.f);
      const float var = sSS2[row]*(1.f/64.f) - mu*mu;
      const float rs = rsqrtf(var + 1e-5f);
      const size_t grow = mbase + row;
      out[grow*64 + col] = (ac2[ct][r]-mu)*rs*gv + bv + feat[grow*64 + col];
    }
  }
}

// ---------------- fused per-neighbor attention kernel (v18, unchanged) ----------------
#define RELP 40
// swizzled address (kept for the tid<128 prologue / reference)
__device__ __forceinline__ u16* swzp(u16* p, int row, int cb){
  return (u16*)((char*)p + row*512 + (cb ^ ((row & 7) << 4)));
}
__global__ __launch_bounds__(1024,4) void attn_k(
    const float* __restrict__ xyz, const int* __restrict__ idxb,
    const u16* __restrict__ lnqkv, const u16* __restrict__ qa, const u16* __restrict__ ka,
    const u16* __restrict__ mcomb, const u16* __restrict__ wp2, const u16* __restrict__ wa2,
    const u16* __restrict__ wp1pk, u16* __restrict__ res){
  __shared__ __attribute__((aligned(16))) u16 h1buf[128*256]; // h1, later v rows (swizzled) 64KB
  __shared__ __attribute__((aligned(16))) u16 h2buf[128*256]; // ka-gather, then h2 (swizzled) 64KB
  __shared__ __attribute__((aligned(16))) u16 qbuf[8*256];    // qa rows (LINEAR) 4KB
  __shared__ __attribute__((aligned(16))) u16 srel[128*RELP]; // 10KB
  __shared__ int sidx[128];
  const int tid = threadIdx.x;
  const int b = blockIdx.x >> 9;
  const int nbase = (blockIdx.x & 511) << 3;
  const size_t gb = (size_t)b << 12;
  if (tid < 128){
    const int m = tid;
    const int im = idxb[(gb + nbase + (m>>4))*16 + (m&15)] & 4095;
    sidx[m] = im;
    const int nn = nbase + (m>>4);
    const float* pq = xyz + (gb+nn)*3;
    const float* pm = xyz + (gb+im)*3;
    const float rx = pq[0]-pm[0], ry = pq[1]-pm[1], rz = pq[2]-pm[2];
    uint4 a; a.x = pk2f(rx,ry); a.y = pk2f(rz,0.f); a.z = 0u; a.w = 0u;
    uint4 z; z.x = z.y = z.z = z.w = 0u;
    *(uint4*)&srel[m*RELP]    = a;
    *(uint4*)&srel[m*RELP+8]  = z;
    *(uint4*)&srel[m*RELP+16] = z;
    *(uint4*)&srel[m*RELP+24] = z;
  }
  __syncthreads();
  const int lane = tid & 63, w = tid >> 6;       // w in 0..15
  const int mrow = lane & 15, quad = lane >> 4;
  const int fr = w << 4;                          // 16 f-rows per wave
  // ---- hoisted swizzled-address bases (all mt/ks terms become immediates)
  const int swc      = (mrow & 7) << 4;                   // row-XOR constant (bytes)
  const int cbst     = (2*(fr + quad*4)) ^ swc;           // C-frag col-block, swizzled
  char* h1st = (char*)h1buf + mrow*512 + cbst;            // + mt*8192 (h1 store)
  char* h2st = (char*)h2buf + mrow*512 + cbst;            // + mt*8192 (pack RMW)
  const int quadoff  = (quad*16) ^ (swc & 0x30);
  const char* h1rd = (const char*)h1buf + mrow*512 + quadoff;  // + ksx + m8*8192
  const char* h2rd = (const char*)h2buf + mrow*512 + quadoff;
  const int ksxc = swc & 0x40;
  // ---- h1 = relu(rel @ Wp1.T): wave covers h-rows [fr,fr+16) x 128 pairs
  {
    bf16x8 aW = *(const bf16x8*)&wp1pk[(fr+mrow)*32 + quad*8];
    #pragma unroll
    for (int mt=0;mt<8;++mt){
      bf16x8 bR = *(const bf16x8*)&srel[(mt*16+mrow)*RELP + quad*8];
      f32x4 hz;
      #pragma unroll
      for (int r=0;r<4;++r) hz[r]=0.f;
      hz = MFMA16(aW, bR, hz);
      float h0 = hz[0]>0.f?hz[0]:0.f, h1v = hz[1]>0.f?hz[1]:0.f;
      float h2v = hz[2]>0.f?hz[2]:0.f, h3 = hz[3]>0.f?hz[3]:0.f;
      uint2 o; o.x = pk2f(h0,h1v); o.y = pk2f(h2v,h3);
      *(uint2*)(h1st + mt*8192) = o;
    }
  }
  __syncthreads();
  // ---- pre-gather: ka rows -> h2buf (all waves), qa rows -> qbuf (waves 0..3, linear).
  // Issued before loop1; the barrier after loop1 drains them (vmcnt(0)).
  {
    #pragma unroll
    for (int i = 0; i < 4; ++i){
      const int row = w*8 + i*2 + (lane>>5);
      const int c   = ((lane&31)*8) ^ ((row & 7) << 3);   // u16 elems, inverse swizzle
      async_copy16(ka + (gb + (size_t)sidx[row])*256 + c,
                   &h2buf[w*2048 + i*512]);
    }
    if (w < 4){
      const int row = w*2 + (lane>>5);
      async_copy16(qa + (gb + nbase + row)*256 + (lane&31)*8, &qbuf[w*512]);
    }
  }
  // ---- loop1: at = mcomb @ h1 ; av = h1 @ wp2.T  (K = 256 over h)
  f32x4 at[8], av[8];
  #pragma unroll
  for (int j=0;j<8;++j)
    #pragma unroll
    for (int r=0;r<4;++r){ at[j][r]=0.f; av[j][r]=0.f; }
  #pragma unroll 1
  for (int ks = 0; ks < 8; ++ks){
    const int koff = ks*32 + quad*8;
    bf16x8 aM = *(const bf16x8*)&mcomb[(fr+mrow)*256 + koff];
    bf16x8 aP = *(const bf16x8*)&wp2  [(fr+mrow)*256 + koff];
    const char* hb = h1rd + ((ks*64) ^ ksxc);
    #pragma unroll
    for (int mh=0; mh<2; ++mh){
      bf16x8 bH[4];
      #pragma unroll
      for (int mi=0;mi<4;++mi) bH[mi] = *(const bf16x8*)(hb + (mh*4+mi)*8192);
      #pragma unroll
      for (int mi=0;mi<4;++mi){
        at[mh*4+mi] = MFMA16(aM, bH[mi], at[mh*4+mi]);
        av[mh*4+mi] = MFMA16(bH[mi], aP, av[mh*4+mi]);
      }
    }
  }
  __syncthreads();   // drains ka/qa gathers; h2buf(ka)+qbuf now visible to all
  // ---- pack: h2 = relu(at + qa - ka) -> bf16 (swizzled, overwrites ka in place)
  #pragma unroll
  for (int mt=0;mt<8;++mt){
    u16* addr = (u16*)(h2st + mt*8192);
    const uint2 kv = *(const uint2*)addr;
    const uint2 qv = *(const uint2*)&qbuf[mt*256 + fr + quad*4];
    float t0 = at[mt][0] + b2f(qv.x&0xffff) - b2f(kv.x&0xffff);
    float t1 = at[mt][1] + b2f(qv.x>>16)    - b2f(kv.x>>16);
    float t2 = at[mt][2] + b2f(qv.y&0xffff) - b2f(kv.y&0xffff);
    float t3 = at[mt][3] + b2f(qv.y>>16)    - b2f(kv.y>>16);
    t0 = t0>0.f?t0:0.f; t1 = t1>0.f?t1:0.f; t2 = t2>0.f?t2:0.f; t3 = t3>0.f?t3:0.f;
    uint2 o; o.x = pk2f(t0,t1); o.y = pk2f(t2,t3);
    *(uint2*)addr = o;
  }
  __syncthreads();
  // ---- async v-gather: linear LDS dest, inverse-swizzled global source (hidden under loop2)
  {
    #pragma unroll
    for (int i = 0; i < 4; ++i){
      const int row = w*8 + i*2 + (lane>>5);
      const int c   = ((lane&31)*8) ^ ((row & 7) << 3);
      async_copy16(lnqkv + (gb + (size_t)sidx[row])*768 + 512 + c,
                   &h1buf[w*2048 + i*512]);
    }
  }
  // ---- loop2: al = h2 @ wa2.T
  f32x4 al[8];
  #pragma unroll
  for (int j=0;j<8;++j)
    #pragma unroll
    for (int r=0;r<4;++r) al[j][r]=0.f;
  #pragma unroll 1
  for (int ks = 0; ks < 8; ++ks){
    const int koff = ks*32 + quad*8;
    bf16x8 aW = *(const bf16x8*)&wa2[(fr+mrow)*256 + koff];
    const char* hb = h2rd + ((ks*64) ^ ksxc);
    #pragma unroll
    for (int mh=0; mh<2; ++mh){
      bf16x8 bH[4];
      #pragma unroll
      for (int mi=0;mi<4;++mi) bH[mi] = *(const bf16x8*)(hb + (mh*4+mi)*8192);
      #pragma unroll
      for (int mi=0;mi<4;++mi) al[mh*4+mi] = MFMA16(bH[mi], aW, al[mh*4+mi]);
    }
  }
  __syncthreads();
  // ---- softmax over the 16 neighbors + weighted reduce of (v + pos)
  const float sc = 0.0901684f;   // log2(e)/sqrt(256)
  // hoisted v-read bases: addr(mt,r) = vb_r + mt*8192 (imm)
  const char* vb0 = (const char*)h1buf + (quad*4+0)*512 + ((2*(fr+mrow)) ^ ((((quad*4)+0)&7)<<4));
  const char* vb1 = (const char*)h1buf + (quad*4+1)*512 + ((2*(fr+mrow)) ^ ((((quad*4)+1)&7)<<4));
  const char* vb2 = (const char*)h1buf + (quad*4+2)*512 + ((2*(fr+mrow)) ^ ((((quad*4)+2)&7)<<4));
  const char* vb3 = (const char*)h1buf + (quad*4+3)*512 + ((2*(fr+mrow)) ^ ((((quad*4)+3)&7)<<4));
  #pragma unroll
  for (int mt=0;mt<8;++mt){
    float prs = 0.f, wgs = 0.f;
    {
      const float val = av[mt][0] + b2f(*(const u16*)(vb0 + mt*8192));
      const float pr = exp2f(al[mt][0]*sc); prs += pr; wgs += pr*val;
    }
    {
      const float val = av[mt][1] + b2f(*(const u16*)(vb1 + mt*8192));
      const float pr = exp2f(al[mt][1]*sc); prs += pr; wgs += pr*val;
    }
    {
      const float val = av[mt][2] + b2f(*(const u16*)(vb2 + mt*8192));
      const float pr = exp2f(al[mt][2]*sc); prs += pr; wgs += pr*val;
    }
    {
      const float val = av[mt][3] + b2f(*(const u16*)(vb3 + mt*8192));
      const float pr = exp2f(al[mt][3]*sc); prs += pr; wgs += pr*val;
    }
    prs += __shfl_xor(prs, 16, 64); prs += __shfl_xor(prs, 32, 64);
    wgs += __shfl_xor(wgs, 16, 64); wgs += __shfl_xor(wgs, 32, 64);
    const float rv = wgs * __builtin_amdgcn_rcpf(prs);
    if (quad == 0)
      res[(gb + nbase + mt)*256 + fr + mrow] = f2b(rv);
  }
}

// ---------------- launcher ----------------
extern "C" void kernel_launch(void* const* d_in, const int* in_sizes, int n_in,
                              void* d_out, int out_size, void* d_ws, size_t ws_size,
                              hipStream_t stream){
  const float* xyz    = (const float*)d_in[0];
  const float* feat   = (const float*)d_in[1];
  const float* W_pre  = (const float*)d_in[2];
  const float* b_pre  = (const float*)d_in[3];
  const float* W_post = (const float*)d_in[4];
  const float* b_post = (const float*)d_in[5];
  const float* Wp1    = (const float*)d_in[6];
  const float* Wp2    = (const float*)d_in[7];
  const float* Wa1    = (const float*)d_in[8];
  const float* Wa2    = (const float*)d_in[9];
  const float* WQ     = (const float*)d_in[10];
  const float* WK     = (const float*)d_in[11];
  const float* WV     = (const float*)d_in[12];
  const float* Wproj  = (const float*)d_in[13];
  const float* g_dm   = (const float*)d_in[14];
  const float* b_dm   = (const float*)d_in[15];
  const float* g_dp   = (const float*)d_in[16];
  const float* b_dp   = (const float*)d_in[17];
  float* out = (float*)d_out;
  if (ws_size < WS_NEED) return;
  char* ws = (char*)d_ws;
  int* idxw   = (int*)(ws + OFF_IDX);
  u16* wqkvb  = (u16*)(ws + OFF_WQKV);
  u16* wa1b   = (u16*)(ws + OFF_WA1);
  u16* wa2b   = (u16*)(ws + OFF_WA2);
  u16* wp2b   = (u16*)(ws + OFF_WP2);
  u16* wprojb = (u16*)(ws + OFF_WPROJ);
  u16* wpostb = (u16*)(ws + OFF_WPOST);
  u16* mcombb = (u16*)(ws + OFF_MCOMB);
  u16* inp    = (u16*)(ws + OFF_INP);
  u16* lnqkv  = (u16*)(ws + OFF_LNQKV);
  u16* qab    = (u16*)(ws + OFF_QA);
  u16* kab    = (u16*)(ws + OFF_KA);
  u16* resb   = (u16*)(ws + OFF_RES);
  u16* wp1pk  = (u16*)(ws + OFF_WP1PK);

  // 1a) weight converts + wp1 pack + mcomb + inp GEMM
  prep_w_k<<<2369,256,0,stream>>>(feat, W_pre, b_pre, WQ, WK, WV, Wa1, Wa2, Wp2,
                                  Wproj, W_post, Wp1,
                                  wqkvb, wa1b, wa2b, wp2b, wprojb, wpostb,
                                  wp1pk, mcombb, inp);
  // 1b) kNN (float4 LDS reads, conflict-free layout; 3 blocks/CU)
  knn_k<<<1024,256,0,stream>>>(xyz, idxw);
  // 2) q: qa = ln(inp@WQ.T)@Wa1.T ; k: ka = ...; v: lnv slice
  gemmlnqa_k<<<dim3(256,1,3),512,0,stream>>>(inp, wqkvb, wa1b, qab, kab, lnqkv, g_dm, b_dm);
  // 3) attention: 2048 blocks x 1024 threads, 8 queries/block
  attn_k<<<2048,1024,0,stream>>>(xyz,idxw,lnqkv,qab,kab,mcombb,wp2b,wa2b,wp1pk,resb);
  // 4) out = ln( ln(res@Wproj.T)@Wpost.T + b_post )*g+b + feat
  projpost_k<<<256,512,0,stream>>>(resb, wprojb, wpostb, b_post, g_dm, b_dm, g_dp, b_dp,
                                   feat, out);
}

// Round 12
// 374.555 us; speedup vs baseline: 1.1260x; 1.0427x over previous
//
#include <hip/hip_runtime.h>
#include <hip/hip_bf16.h>

typedef unsigned short u16;
typedef unsigned int   u32;
typedef __attribute__((ext_vector_type(8))) short bf16x8;
typedef __attribute__((ext_vector_type(4))) float f32x4;

#define MFMA16(a,b,c) __builtin_amdgcn_mfma_f32_16x16x32_bf16((a),(b),(c),0,0,0)

__device__ __forceinline__ float b2f(u32 h){ return __uint_as_float(h<<16); }
__device__ __forceinline__ u16 f2b(float f){
  u32 u = __float_as_uint(f);
  return (u16)((u + 0x7FFFu + ((u>>16)&1u))>>16);
}
// HW packed convert: v_cvt_pk_bf16_f32 (RNE)
__device__ __forceinline__ u32 pk2f(float a,float b){
  __hip_bfloat162 h = __float22bfloat162_rn(float2{a,b});
  return *reinterpret_cast<u32*>(&h);
}
__device__ __forceinline__ u32 umin32(u32 a,u32 b){ return a<b?a:b; }
__device__ __forceinline__ u32 umax32(u32 a,u32 b){ return a>b?a:b; }

// 16-lane row-sum on the VALU pipe via DPP row_ror
template<int CTRL>
__device__ __forceinline__ float dpp_add(float x){
  int t = __builtin_amdgcn_update_dpp(0, __float_as_int(x), CTRL, 0xF, 0xF, true);
  return x + __int_as_float(t);
}
__device__ __forceinline__ float rowsum16(float x){
  x = dpp_add<0x121>(x);
  x = dpp_add<0x122>(x);
  x = dpp_add<0x124>(x);
  x = dpp_add<0x128>(x);
  return x;
}

__device__ __forceinline__ void async_copy16(const void* g, void* l){
  __builtin_amdgcn_global_load_lds((const __attribute__((address_space(1))) u32*)g,
                                   (__attribute__((address_space(3))) u32*)l, 16, 0, 0);
}

// ---------------- workspace layout (bytes) ----------------
#define OFF_IDX    0ull
#define OFF_WQKV   3178496ull
#define OFF_WA1    3571712ull
#define OFF_WA2    3702784ull
#define OFF_WP2    3833856ull
#define OFF_WPROJ  3964928ull
#define OFF_WPOST  4096000ull
#define OFF_MCOMB  4128768ull
#define OFF_INP    4259840ull
#define OFF_LNQKV  37814272ull
#define OFF_QA     62980096ull
#define OFF_KA     71368704ull
#define OFF_RES    79757312ull
#define OFF_D1     88145920ull
#define WS_NEED    104923136ull
#define OFF_WP1PK  OFF_D1

// ---------------- kNN insertion: a[j] = med3(a[j-1], key, a[j]) ----------------
// Given sorted a[0..15] ascending, min(max(a[j-1],key),a[j]) == median3 of the
// three. v_med3_u32 replaces the 2-op min/max pair -> 16 instr per candidate.
__device__ __forceinline__ void ins16(u32 (&a)[16], u32 key){
  #pragma unroll
  for (int j = 15; j >= 1; --j){
    u32 r;
    asm("v_med3_u32 %0, %1, %2, %3" : "=v"(r) : "v"(a[j-1]), "v"(key), "v"(a[j]));
    a[j] = r;
  }
  a[0] = umin32(a[0], key);
}

__device__ __forceinline__ float dist2(float ax,float ay,float az,float bx,float by,float bz){
  const float dx = ax-bx, dy = ay-by, dz = az-bz;
  return __fmaf_rn(dx,dx, __fmaf_rn(dy,dy, dz*dz));
}

// ---------------- merged prep: kNN (blocks 0..1023, dispatched FIRST) +
//                  weight converts / wp1 pack / mcomb / inp GEMM (blocks 1024..3392)
// Both roles are 256-thread fully-active blocks, uniform 51.2KB LDS (2-3 blocks/CU
// either way) -- the safe form of the R10 merge (whose failure was half-idle
// 512-thread knn blocks + occupancy drop). kNN's long VALU-bound blocks fill the
// machine first; prep's short HBM-bound blocks stream in behind -> pipe overlap.
__global__ __launch_bounds__(256,2) void prep_k(
    const float* __restrict__ xyz, const float* __restrict__ feat,
    const float* __restrict__ wpre, const float* __restrict__ bpre,
    const float* __restrict__ wq, const float* __restrict__ wk, const float* __restrict__ wv,
    const float* __restrict__ wa1, const float* __restrict__ wa2, const float* __restrict__ wp2,
    const float* __restrict__ wproj, const float* __restrict__ wpost,
    const float* __restrict__ wp1,
    u16* __restrict__ dwqkv, u16* __restrict__ dwa1, u16* __restrict__ dwa2,
    u16* __restrict__ dwp2, u16* __restrict__ dwproj, u16* __restrict__ dwpost,
    u16* __restrict__ dwp1pk, u16* __restrict__ dmcomb,
    int* __restrict__ idxout, u16* __restrict__ dinp){
  __shared__ __attribute__((aligned(16))) char smem[51200];
  const int bid0 = blockIdx.x, tid = threadIdx.x;
  if (bid0 < 1024){
    // ---------------- kNN role ----------------
    float* sx = (float*)smem;              // [16][260]
    float* sy = sx + 4160;
    float* sz = sy + 4160;                 // ends at byte 49920
    int* lcnt   = (int*)(smem + 49920);
    int* tcnt   = (int*)(smem + 49984);
    u32* tbuf   = (u32*)(smem + 50048);
    int* tiebuf = (int*)(smem + 50112);    // 1024 B -> 51136
    const int b  = bid0 >> 8;
    const int n0 = (bid0 & 255) << 4;
    const float* base = xyz + (size_t)b*12288;
    #pragma unroll
    for (int i = 0; i < 12; ++i){
      const float4 v = *(const float4*)(base + tid*48 + i*4);
      const float vv[4] = {v.x, v.y, v.z, v.w};
      #pragma unroll
      for (int j = 0; j < 4; ++j){
        const int e = i*4 + j;
        const int c = e % 3;
        const int m = tid*16 + e/3;
        float* arr = (c==0)?sx:((c==1)?sy:sz);
        arr[(m>>8)*260 + (m&255)] = vv[j];
      }
    }
    if (tid < 16){ lcnt[tid] = 0; tcnt[tid] = 0; }
    __syncthreads();
    const int qi = tid >> 4, p = tid & 15;
    const int n = n0 + qi;
    const float qx = sx[(n>>8)*260 + (n&255)];
    const float qy = sy[(n>>8)*260 + (n&255)];
    const float qz = sz[(n>>8)*260 + (n&255)];
    u32 a[16];
    #pragma unroll
    for (int j = 0; j < 16; ++j) a[j] = 0xFFFFFFFFu;
    const float* px = sx + p*260;
    const float* py = sy + p*260;
    const float* pz = sz + p*260;
    #pragma unroll 2
    for (int i4 = 0; i4 < 64; ++i4){
      const float4 x4 = *(const float4*)(px + i4*4);
      const float4 y4 = *(const float4*)(py + i4*4);
      const float4 z4 = *(const float4*)(pz + i4*4);
      ins16(a, __float_as_uint(dist2(x4.x,y4.x,z4.x,qx,qy,qz)));
      ins16(a, __float_as_uint(dist2(x4.y,y4.y,z4.y,qx,qy,qz)));
      ins16(a, __float_as_uint(dist2(x4.z,y4.z,z4.z,qx,qy,qz)));
      ins16(a, __float_as_uint(dist2(x4.w,y4.w,z4.w,qx,qy,qz)));
    }
    #pragma unroll
    for (int s = 8; s >= 1; s >>= 1){
      u32 o[16];
      #pragma unroll
      for (int j = 0; j < 16; ++j) o[j] = __shfl_down(a[j], (unsigned)s, 64);
      if (p < s){
        #pragma unroll
        for (int j = 0; j < 16; ++j) ins16(a, o[j]);
      }
    }
    if (p == 0) tbuf[qi] = a[15];
    __syncthreads();
    const u32 T = tbuf[qi];
    int* orow = idxout + ((size_t)(b<<12)+n)*16;
    const int gbase = p*256;
    for (int i4 = 0; i4 < 64; ++i4){
      const float4 x4 = *(const float4*)(px + i4*4);
      const float4 y4 = *(const float4*)(py + i4*4);
      const float4 z4 = *(const float4*)(pz + i4*4);
      const float xv[4] = {x4.x,x4.y,x4.z,x4.w};
      const float yv[4] = {y4.x,y4.y,y4.z,y4.w};
      const float zv[4] = {z4.x,z4.y,z4.z,z4.w};
      #pragma unroll
      for (int j = 0; j < 4; ++j){
        const float d2 = dist2(xv[j],yv[j],zv[j],qx,qy,qz);
        const u32 kb = __float_as_uint(d2);
        if (kb < T){
          const int pos = atomicAdd(&lcnt[qi],1);
          if (pos < 16) orow[pos] = gbase + i4*4 + j;
        } else if (kb == T){
          const int t = atomicAdd(&tcnt[qi],1);
          if (t < 16) tiebuf[qi*16+t] = gbase + i4*4 + j;
        }
      }
    }
    __syncthreads();
    if (p == 0){
      int L = lcnt[qi]; if (L > 16) L = 16;
      int tc = tcnt[qi]; if (tc > 16) tc = 16;
      const int need = 16 - L;
      for (int r = 0; r < need; ++r){
        int best = 0x7FFFFFFF, bj = -1;
        for (int j = 0; j < tc; ++j){
          const int v = tiebuf[qi*16+j];
          if (v < best){ best = v; bj = j; }
        }
        if (bj >= 0){ tiebuf[qi*16+bj] = 0x7FFFFFFF; orow[L+r] = best; }
        else orow[L+r] = n;
      }
    }
    return;
  }
  const int bid = bid0 - 1024;   // 0..2368
  if (bid < 1856){
    int id = bid*256 + tid;
    const float* s; u16* d; int off;
    if      (id <  65536){ s=wq;    d=dwqkv;        off=id; }
    else if (id < 131072){ s=wk;    d=dwqkv+65536;  off=id-65536; }
    else if (id < 196608){ s=wv;    d=dwqkv+131072; off=id-131072; }
    else if (id < 262144){ s=wa1;   d=dwa1;         off=id-196608; }
    else if (id < 327680){ s=wa2;   d=dwa2;         off=id-262144; }
    else if (id < 393216){ s=wp2;   d=dwp2;         off=id-327680; }
    else if (id < 458752){ s=wproj; d=dwproj;       off=id-393216; }
    else                 { s=wpost; d=dwpost;       off=id-458752; }
    d[off] = f2b(s[off]);
  } else if (bid == 1856){
    const int h = tid;
    const float w0 = wp1[h*3], w1 = wp1[h*3+1], w2 = wp1[h*3+2];
    uint4 a; a.x = pk2f(w0,w1); a.y = pk2f(w2,0.f); a.z = 0u; a.w = 0u;
    uint4 z; z.x = z.y = z.z = z.w = 0u;
    *(uint4*)&dwp1pk[h*32]    = a;
    *(uint4*)&dwp1pk[h*32+8]  = z;
    *(uint4*)&dwp1pk[h*32+16] = z;
    *(uint4*)&dwp1pk[h*32+24] = z;
  } else if (bid < 2113){
    const int f = bid - 1857, h = tid;
    float acc = 0.f;
    #pragma unroll 4
    for (int j = 0; j < 256; ++j) acc = __fmaf_rn(wa1[f*256+j], wp2[j*256+h], acc);
    dmcomb[f*256+h] = f2b(acc);
  } else {
    // ---- inp = feat @ W_pre.T + b_pre (K=64), 128x128 tile
    u16* As = (u16*)smem;            // [128][72]
    u16* Bs = (u16*)smem + 9216;     // [128][72]
    const int tb = bid - 2113;
    const int mb = tb >> 1, nb = tb & 1;
    #pragma unroll
    for (int i = 0; i < 32; ++i){
      const int e = i*256 + tid;
      const int row = e >> 6, k = e & 63;
      As[row*72+k] = f2b(feat[(size_t)(mb*128)*64 + e]);
      Bs[row*72+k] = f2b(wpre[(size_t)(nb*128)*64 + e]);
    }
    __syncthreads();
    const int lane = tid & 63, w = tid >> 6;
    const int mrow = lane & 15, quad = lane >> 4;
    const int wr = (w&1)*64, wc = (w>>1)*64;
    f32x4 acc[4][4];
    #pragma unroll
    for (int i=0;i<4;++i)
      #pragma unroll
      for (int j=0;j<4;++j)
        #pragma unroll
        for (int r=0;r<4;++r) acc[i][j][r] = 0.f;
    #pragma unroll
    for (int ks = 0; ks < 2; ++ks){
      const int koff = ks*32 + quad*8;
      bf16x8 af[4], bf[4];
      #pragma unroll
      for (int rt=0;rt<4;++rt) af[rt] = *(const bf16x8*)&As[(wr+rt*16+mrow)*72 + koff];
      #pragma unroll
      for (int ct=0;ct<4;++ct) bf[ct] = *(const bf16x8*)&Bs[(wc+ct*16+mrow)*72 + koff];
      #pragma unroll
      for (int rt=0;rt<4;++rt)
        #pragma unroll
        for (int ct=0;ct<4;++ct) acc[rt][ct] = MFMA16(af[rt], bf[ct], acc[rt][ct]);
    }
    #pragma unroll
    for (int rt=0;rt<4;++rt)
      #pragma unroll
      for (int ct=0;ct<4;++ct){
        const size_t row0 = (size_t)mb*128 + wr + rt*16 + quad*4;
        const int col = nb*128 + wc + ct*16 + mrow;
        const float bv = bpre[col];
        #pragma unroll
        for (int r=0;r<4;++r) dinp[(row0+r)*256 + col] = f2b(acc[rt][ct][r] + bv);
      }
  }
}

// ---------------- fused GEMM+LN (+second GEMM for qa/ka): 64-row tiles ----------------
// z=0: qa = ln(inp@WQ.T) @ Wa1.T   z=1: ka = ln(inp@WK.T) @ Wa1.T
// z=2: lnv slice = ln(inp@WV.T)  (written to lnqkv[...,512:768])
// 512 threads = 8 waves. Phase1 wave: rows (w&1)*32..+32, cols (w>>1)*64..+64.
#define LNP 264
__global__ __launch_bounds__(512,2) void gemmlnqa_k(
    const u16* __restrict__ inp, const u16* __restrict__ wqkv, const u16* __restrict__ wa1,
    u16* __restrict__ qa, u16* __restrict__ ka, u16* __restrict__ lnqkv,
    const float* __restrict__ g, const float* __restrict__ bta){
  __shared__ __attribute__((aligned(16))) u16 As[64*32];      // 4 KB
  __shared__ __attribute__((aligned(16))) u16 Bs[256*32];     // 16 KB
  __shared__ __attribute__((aligned(16))) u16 lnbuf[64*LNP];  // 33.8 KB
  __shared__ float sS[64], sSS[64];
  const int z = blockIdx.z;
  const u16* wsel = wqkv + z*65536;
  const int tid = threadIdx.x, lane = tid & 63, w = tid >> 6;
  const int mrow = lane & 15, quad = lane >> 4;
  const size_t mbase = (size_t)blockIdx.x*64;
  const int wr = (w&1)*32, wc = (w>>1)*64;
  if (tid < 64){ sS[tid] = 0.f; sSS[tid] = 0.f; }
  f32x4 acc[2][4];
  #pragma unroll
  for (int i=0;i<2;++i)
    #pragma unroll
    for (int j=0;j<4;++j)
      #pragma unroll
      for (int r=0;r<4;++r) acc[i][j][r] = 0.f;
  const int sr = tid >> 2, sk = (tid & 3)*8;
  // ---- phase 1: X = inp(64 rows) @ wsel.T
  for (int k0 = 0; k0 < 256; k0 += 32){
    __syncthreads();
    if (tid < 256) async_copy16(inp + (mbase + sr)*256 + k0 + sk, &As[w*512]);
    async_copy16(wsel + (size_t)sr*256       + k0 + sk, &Bs[w*512]);
    async_copy16(wsel + (size_t)(128+sr)*256 + k0 + sk, &Bs[4096 + w*512]);
    __syncthreads();
    bf16x8 af[2], bf[4];
    #pragma unroll
    for (int rt=0;rt<2;++rt) af[rt] = *(const bf16x8*)&As[(wr+rt*16+mrow)*32 + quad*8];
    #pragma unroll
    for (int ct=0;ct<4;++ct) bf[ct] = *(const bf16x8*)&Bs[(wc+ct*16+mrow)*32 + quad*8];
    #pragma unroll
    for (int rt=0;rt<2;++rt)
      #pragma unroll
      for (int ct=0;ct<4;++ct) acc[rt][ct] = MFMA16(af[rt], bf[ct], acc[rt][ct]);
  }
  // row stats (f32) across 4 col-waves
  #pragma unroll
  for (int rt=0;rt<2;++rt)
    #pragma unroll
    for (int r=0;r<4;++r){
      float s  = acc[rt][0][r]+acc[rt][1][r]+acc[rt][2][r]+acc[rt][3][r];
      float ss = acc[rt][0][r]*acc[rt][0][r]+acc[rt][1][r]*acc[rt][1][r]
               + acc[rt][2][r]*acc[rt][2][r]+acc[rt][3][r]*acc[rt][3][r];
      s  = rowsum16(s);
      ss = rowsum16(ss);
      if (mrow == 0){
        const int row = wr + rt*16 + quad*4 + r;
        atomicAdd(&sS[row],  s);
        atomicAdd(&sSS[row], ss);
      }
    }
  __syncthreads();
  // apply LN
  #pragma unroll
  for (int ct=0;ct<4;++ct){
    const int col = wc + ct*16 + mrow;
    const float gv = g[col], bv = bta[col];
    #pragma unroll
    for (int rt=0;rt<2;++rt)
      #pragma unroll
      for (int r=0;r<4;++r){
        const int row = wr + rt*16 + quad*4 + r;
        const float mu = sS[row]*(1.f/256.f);
        const float var = sSS[row]*(1.f/256.f) - mu*mu;
        const float rs = rsqrtf(var + 1e-5f);
        const u16 hv = f2b((acc[rt][ct][r]-mu)*rs*gv + bv);
        if (z == 2) lnqkv[(mbase+row)*768 + 512 + col] = hv;
        else        lnbuf[row*LNP + col] = hv;
      }
  }
  if (z == 2) return;
  // ---- phase 2: out = lnbuf @ Wa1.T  (Bs restaged per k-step)
  u16* outp = (z == 0) ? qa : ka;
  f32x4 ac2[2][4];
  #pragma unroll
  for (int i=0;i<2;++i)
    #pragma unroll
    for (int j=0;j<4;++j)
      #pragma unroll
      for (int r=0;r<4;++r) ac2[i][j][r] = 0.f;
  for (int k0 = 0; k0 < 256; k0 += 32){
    __syncthreads();
    async_copy16(wa1 + (size_t)sr*256       + k0 + sk, &Bs[w*512]);
    async_copy16(wa1 + (size_t)(128+sr)*256 + k0 + sk, &Bs[4096 + w*512]);
    __syncthreads();
    bf16x8 af[2], bf[4];
    #pragma unroll
    for (int rt=0;rt<2;++rt) af[rt] = *(const bf16x8*)&lnbuf[(wr+rt*16+mrow)*LNP + k0 + quad*8];
    #pragma unroll
    for (int ct=0;ct<4;++ct) bf[ct] = *(const bf16x8*)&Bs[(wc+ct*16+mrow)*32 + quad*8];
    #pragma unroll
    for (int rt=0;rt<2;++rt)
      #pragma unroll
      for (int ct=0;ct<4;++ct) ac2[rt][ct] = MFMA16(af[rt], bf[ct], ac2[rt][ct]);
  }
  #pragma unroll
  for (int rt=0;rt<2;++rt)
    #pragma unroll
    for (int ct=0;ct<4;++ct){
      const size_t row0 = mbase + wr + rt*16 + quad*4;
      const int col = wc + ct*16 + mrow;
      #pragma unroll
      for (int r=0;r<4;++r) outp[(row0+r)*256 + col] = f2b(ac2[rt][ct][r]);
    }
}

// ---------------- fused: out = ln( ln(res@Wproj.T) @ Wpost.T + bpost )*g+b + feat ----------------
// 64-row tiles, 512 threads. Phase1 like gemmlnqa. Phase2: 64 cols; wave = 16 rows x 32 cols.
__global__ __launch_bounds__(512,2) void projpost_k(
    const u16* __restrict__ res, const u16* __restrict__ wproj, const u16* __restrict__ wpost,
    const float* __restrict__ bpost,
    const float* __restrict__ g_dm, const float* __restrict__ b_dm,
    const float* __restrict__ g_dp, const float* __restrict__ b_dp,
    const float* __restrict__ feat, float* __restrict__ out){
  __shared__ __attribute__((aligned(16))) u16 As[64*32];
  __shared__ __attribute__((aligned(16))) u16 Bs[256*32];
  __shared__ __attribute__((aligned(16))) u16 lnbuf[64*LNP];
  __shared__ float sS[64], sSS[64], sS2[64], sSS2[64];
  const int tid = threadIdx.x, lane = tid & 63, w = tid >> 6;
  const int mrow = lane & 15, quad = lane >> 4;
  const size_t mbase = (size_t)blockIdx.x*64;
  const int wr = (w&1)*32, wc = (w>>1)*64;
  if (tid < 64){ sS[tid]=0.f; sSS[tid]=0.f; sS2[tid]=0.f; sSS2[tid]=0.f; }
  f32x4 acc[2][4];
  #pragma unroll
  for (int i=0;i<2;++i)
    #pragma unroll
    for (int j=0;j<4;++j)
      #pragma unroll
      for (int r=0;r<4;++r) acc[i][j][r] = 0.f;
  const int sr = tid >> 2, sk = (tid & 3)*8;
  for (int k0 = 0; k0 < 256; k0 += 32){
    __syncthreads();
    if (tid < 256) async_copy16(res + (mbase + sr)*256 + k0 + sk, &As[w*512]);
    async_copy16(wproj + (size_t)sr*256       + k0 + sk, &Bs[w*512]);
    async_copy16(wproj + (size_t)(128+sr)*256 + k0 + sk, &Bs[4096 + w*512]);
    __syncthreads();
    bf16x8 af[2], bf[4];
    #pragma unroll
    for (int rt=0;rt<2;++rt) af[rt] = *(const bf16x8*)&As[(wr+rt*16+mrow)*32 + quad*8];
    #pragma unroll
    for (int ct=0;ct<4;++ct) bf[ct] = *(const bf16x8*)&Bs[(wc+ct*16+mrow)*32 + quad*8];
    #pragma unroll
    for (int rt=0;rt<2;++rt)
      #pragma unroll
      for (int ct=0;ct<4;++ct) acc[rt][ct] = MFMA16(af[rt], bf[ct], acc[rt][ct]);
  }
  #pragma unroll
  for (int rt=0;rt<2;++rt)
    #pragma unroll
    for (int r=0;r<4;++r){
      float s  = acc[rt][0][r]+acc[rt][1][r]+acc[rt][2][r]+acc[rt][3][r];
      float ss = acc[rt][0][r]*acc[rt][0][r]+acc[rt][1][r]*acc[rt][1][r]
               + acc[rt][2][r]*acc[rt][2][r]+acc[rt][3][r]*acc[rt][3][r];
      s  = rowsum16(s);
      ss = rowsum16(ss);
      if (mrow == 0){
        const int row = wr + rt*16 + quad*4 + r;
        atomicAdd(&sS[row],  s);
        atomicAdd(&sSS[row], ss);
      }
    }
  __syncthreads();
  #pragma unroll
  for (int ct=0;ct<4;++ct){
    const int col = wc + ct*16 + mrow;
    const float gv = g_dm[col], bv = b_dm[col];
    #pragma unroll
    for (int rt=0;rt<2;++rt)
      #pragma unroll
      for (int r=0;r<4;++r){
        const int row = wr + rt*16 + quad*4 + r;
        const float mu = sS[row]*(1.f/256.f);
        const float var = sSS[row]*(1.f/256.f) - mu*mu;
        const float rs = rsqrtf(var + 1e-5f);
        lnbuf[row*LNP + col] = f2b((acc[rt][ct][r]-mu)*rs*gv + bv);
      }
  }
  // ---- phase 2: d = lnbuf @ Wpost.T + bpost  (64 cols); wave = 16 rows x 32 cols
  const int wr2 = (w & 3)*16, wc2 = (w >> 2)*32;
  f32x4 ac2[2];
  #pragma unroll
  for (int j=0;j<2;++j)
    #pragma unroll
    for (int r=0;r<4;++r) ac2[j][r] = 0.f;
  for (int k0 = 0; k0 < 256; k0 += 32){
    __syncthreads();
    if (tid < 256) async_copy16(wpost + (size_t)sr*256 + k0 + sk, &Bs[w*512]);
    __syncthreads();
    bf16x8 af, bf[2];
    af = *(const bf16x8*)&lnbuf[(wr2+mrow)*LNP + k0 + quad*8];
    #pragma unroll
    for (int ct=0;ct<2;++ct) bf[ct] = *(const bf16x8*)&Bs[(wc2+ct*16+mrow)*32 + quad*8];
    #pragma unroll
    for (int ct=0;ct<2;++ct) ac2[ct] = MFMA16(af, bf[ct], ac2[ct]);
  }
  #pragma unroll
  for (int ct=0;ct<2;++ct){
    const float bv = bpost[wc2 + ct*16 + mrow];
    #pragma unroll
    for (int r=0;r<4;++r) ac2[ct][r] += bv;
  }
  #pragma unroll
  for (int r=0;r<4;++r){
    float s  = ac2[0][r] + ac2[1][r];
    float ss = ac2[0][r]*ac2[0][r] + ac2[1][r]*ac2[1][r];
    s  = rowsum16(s);
    ss = rowsum16(ss);
    if (mrow == 0){
      const int row = wr2 + quad*4 + r;
      atomicAdd(&sS2[row],  s);
      atomicAdd(&sSS2[row], ss);
    }
  }
  __syncthreads();
  #pragma unroll
  for (int ct=0;ct<2;++ct){
    const int col = wc2 + ct*16 + mrow;
    const float gv = g_dp[col], bv = b_dp[col];
    #pragma unroll
    for (int r=0;r<4;++r){
      const int row = wr2 + quad*4 + r;
      const float mu = sS2[row]*(1.f/64.f);
      const float var = sSS2[row]*(1.f/64.f) - mu*mu;
      const float rs = rsqrtf(var + 1e-5f);
      const size_t grow = mbase + row;
      out[grow*64 + col] = (ac2[ct][r]-mu)*rs*gv + bv + feat[grow*64 + col];
    }
  }
}

// ---------------- fused per-neighbor attention kernel (v18, unchanged) ----------------
#define RELP 40
// swizzled address (kept for the tid<128 prologue / reference)
__device__ __forceinline__ u16* swzp(u16* p, int row, int cb){
  return (u16*)((char*)p + row*512 + (cb ^ ((row & 7) << 4)));
}
__global__ __launch_bounds__(1024,4) void attn_k(
    const float* __restrict__ xyz, const int* __restrict__ idxb,
    const u16* __restrict__ lnqkv, const u16* __restrict__ qa, const u16* __restrict__ ka,
    const u16* __restrict__ mcomb, const u16* __restrict__ wp2, const u16* __restrict__ wa2,
    const u16* __restrict__ wp1pk, u16* __restrict__ res){
  __shared__ __attribute__((aligned(16))) u16 h1buf[128*256]; // h1, later v rows (swizzled) 64KB
  __shared__ __attribute__((aligned(16))) u16 h2buf[128*256]; // ka-gather, then h2 (swizzled) 64KB
  __shared__ __attribute__((aligned(16))) u16 qbuf[8*256];    // qa rows (LINEAR) 4KB
  __shared__ __attribute__((aligned(16))) u16 srel[128*RELP]; // 10KB
  __shared__ int sidx[128];
  const int tid = threadIdx.x;
  const int b = blockIdx.x >> 9;
  const int nbase = (blockIdx.x & 511) << 3;
  const size_t gb = (size_t)b << 12;
  if (tid < 128){
    const int m = tid;
    const int im = idxb[(gb + nbase + (m>>4))*16 + (m&15)] & 4095;
    sidx[m] = im;
    const int nn = nbase + (m>>4);
    const float* pq = xyz + (gb+nn)*3;
    const float* pm = xyz + (gb+im)*3;
    const float rx = pq[0]-pm[0], ry = pq[1]-pm[1], rz = pq[2]-pm[2];
    uint4 a; a.x = pk2f(rx,ry); a.y = pk2f(rz,0.f); a.z = 0u; a.w = 0u;
    uint4 z; z.x = z.y = z.z = z.w = 0u;
    *(uint4*)&srel[m*RELP]    = a;
    *(uint4*)&srel[m*RELP+8]  = z;
    *(uint4*)&srel[m*RELP+16] = z;
    *(uint4*)&srel[m*RELP+24] = z;
  }
  __syncthreads();
  const int lane = tid & 63, w = tid >> 6;       // w in 0..15
  const int mrow = lane & 15, quad = lane >> 4;
  const int fr = w << 4;                          // 16 f-rows per wave
  // ---- hoisted swizzled-address bases (all mt/ks terms become immediates)
  const int swc      = (mrow & 7) << 4;                   // row-XOR constant (bytes)
  const int cbst     = (2*(fr + quad*4)) ^ swc;           // C-frag col-block, swizzled
  char* h1st = (char*)h1buf + mrow*512 + cbst;            // + mt*8192 (h1 store)
  char* h2st = (char*)h2buf + mrow*512 + cbst;            // + mt*8192 (pack RMW)
  const int quadoff  = (quad*16) ^ (swc & 0x30);
  const char* h1rd = (const char*)h1buf + mrow*512 + quadoff;  // + ksx + m8*8192
  const char* h2rd = (const char*)h2buf + mrow*512 + quadoff;
  const int ksxc = swc & 0x40;
  // ---- h1 = relu(rel @ Wp1.T): wave covers h-rows [fr,fr+16) x 128 pairs
  {
    bf16x8 aW = *(const bf16x8*)&wp1pk[(fr+mrow)*32 + quad*8];
    #pragma unroll
    for (int mt=0;mt<8;++mt){
      bf16x8 bR = *(const bf16x8*)&srel[(mt*16+mrow)*RELP + quad*8];
      f32x4 hz;
      #pragma unroll
      for (int r=0;r<4;++r) hz[r]=0.f;
      hz = MFMA16(aW, bR, hz);
      float h0 = hz[0]>0.f?hz[0]:0.f, h1v = hz[1]>0.f?hz[1]:0.f;
      float h2v = hz[2]>0.f?hz[2]:0.f, h3 = hz[3]>0.f?hz[3]:0.f;
      uint2 o; o.x = pk2f(h0,h1v); o.y = pk2f(h2v,h3);
      *(uint2*)(h1st + mt*8192) = o;
    }
  }
  __syncthreads();
  // ---- pre-gather: ka rows -> h2buf (all waves), qa rows -> qbuf (waves 0..3, linear).
  // Issued before loop1; the barrier after loop1 drains them (vmcnt(0)).
  {
    #pragma unroll
    for (int i = 0; i < 4; ++i){
      const int row = w*8 + i*2 + (lane>>5);
      const int c   = ((lane&31)*8) ^ ((row & 7) << 3);   // u16 elems, inverse swizzle
      async_copy16(ka + (gb + (size_t)sidx[row])*256 + c,
                   &h2buf[w*2048 + i*512]);
    }
    if (w < 4){
      const int row = w*2 + (lane>>5);
      async_copy16(qa + (gb + nbase + row)*256 + (lane&31)*8, &qbuf[w*512]);
    }
  }
  // ---- loop1: at = mcomb @ h1 ; av = h1 @ wp2.T  (K = 256 over h)
  f32x4 at[8], av[8];
  #pragma unroll
  for (int j=0;j<8;++j)
    #pragma unroll
    for (int r=0;r<4;++r){ at[j][r]=0.f; av[j][r]=0.f; }
  #pragma unroll 1
  for (int ks = 0; ks < 8; ++ks){
    const int koff = ks*32 + quad*8;
    bf16x8 aM = *(const bf16x8*)&mcomb[(fr+mrow)*256 + koff];
    bf16x8 aP = *(const bf16x8*)&wp2  [(fr+mrow)*256 + koff];
    const char* hb = h1rd + ((ks*64) ^ ksxc);
    #pragma unroll
    for (int mh=0; mh<2; ++mh){
      bf16x8 bH[4];
      #pragma unroll
      for (int mi=0;mi<4;++mi) bH[mi] = *(const bf16x8*)(hb + (mh*4+mi)*8192);
      #pragma unroll
      for (int mi=0;mi<4;++mi){
        at[mh*4+mi] = MFMA16(aM, bH[mi], at[mh*4+mi]);
        av[mh*4+mi] = MFMA16(bH[mi], aP, av[mh*4+mi]);
      }
    }
  }
  __syncthreads();   // drains ka/qa gathers; h2buf(ka)+qbuf now visible to all
  // ---- pack: h2 = relu(at + qa - ka) -> bf16 (swizzled, overwrites ka in place)
  #pragma unroll
  for (int mt=0;mt<8;++mt){
    u16* addr = (u16*)(h2st + mt*8192);
    const uint2 kv = *(const uint2*)addr;
    const uint2 qv = *(const uint2*)&qbuf[mt*256 + fr + quad*4];
    float t0 = at[mt][0] + b2f(qv.x&0xffff) - b2f(kv.x&0xffff);
    float t1 = at[mt][1] + b2f(qv.x>>16)    - b2f(kv.x>>16);
    float t2 = at[mt][2] + b2f(qv.y&0xffff) - b2f(kv.y&0xffff);
    float t3 = at[mt][3] + b2f(qv.y>>16)    - b2f(kv.y>>16);
    t0 = t0>0.f?t0:0.f; t1 = t1>0.f?t1:0.f; t2 = t2>0.f?t2:0.f; t3 = t3>0.f?t3:0.f;
    uint2 o; o.x = pk2f(t0,t1); o.y = pk2f(t2,t3);
    *(uint2*)addr = o;
  }
  __syncthreads();
  // ---- async v-gather: linear LDS dest, inverse-swizzled global source (hidden under loop2)
  {
    #pragma unroll
    for (int i = 0; i < 4; ++i){
      const int row = w*8 + i*2 + (lane>>5);
      const int c   = ((lane&31)*8) ^ ((row & 7) << 3);
      async_copy16(lnqkv + (gb + (size_t)sidx[row])*768 + 512 + c,
                   &h1buf[w*2048 + i*512]);
    }
  }
  // ---- loop2: al = h2 @ wa2.T
  f32x4 al[8];
  #pragma unroll
  for (int j=0;j<8;++j)
    #pragma unroll
    for (int r=0;r<4;++r) al[j][r]=0.f;
  #pragma unroll 1
  for (int ks = 0; ks < 8; ++ks){
    const int koff = ks*32 + quad*8;
    bf16x8 aW = *(const bf16x8*)&wa2[(fr+mrow)*256 + koff];
    const char* hb = h2rd + ((ks*64) ^ ksxc);
    #pragma unroll
    for (int mh=0; mh<2; ++mh){
      bf16x8 bH[4];
      #pragma unroll
      for (int mi=0;mi<4;++mi) bH[mi] = *(const bf16x8*)(hb + (mh*4+mi)*8192);
      #pragma unroll
      for (int mi=0;mi<4;++mi) al[mh*4+mi] = MFMA16(bH[mi], aW, al[mh*4+mi]);
    }
  }
  __syncthreads();
  // ---- softmax over the 16 neighbors + weighted reduce of (v + pos)
  const float sc = 0.0901684f;   // log2(e)/sqrt(256)
  // hoisted v-read bases: addr(mt,r) = vb_r + mt*8192 (imm)
  const char* vb0 = (const char*)h1buf + (quad*4+0)*512 + ((2*(fr+mrow)) ^ ((((quad*4)+0)&7)<<4));
  const char* vb1 = (const char*)h1buf + (quad*4+1)*512 + ((2*(fr+mrow)) ^ ((((quad*4)+1)&7)<<4));
  const char* vb2 = (const char*)h1buf + (quad*4+2)*512 + ((2*(fr+mrow)) ^ ((((quad*4)+2)&7)<<4));
  const char* vb3 = (const char*)h1buf + (quad*4+3)*512 + ((2*(fr+mrow)) ^ ((((quad*4)+3)&7)<<4));
  #pragma unroll
  for (int mt=0;mt<8;++mt){
    float prs = 0.f, wgs = 0.f;
    {
      const float val = av[mt][0] + b2f(*(const u16*)(vb0 + mt*8192));
      const float pr = exp2f(al[mt][0]*sc); prs += pr; wgs += pr*val;
    }
    {
      const float val = av[mt][1] + b2f(*(const u16*)(vb1 + mt*8192));
      const float pr = exp2f(al[mt][1]*sc); prs += pr; wgs += pr*val;
    }
    {
      const float val = av[mt][2] + b2f(*(const u16*)(vb2 + mt*8192));
      const float pr = exp2f(al[mt][2]*sc); prs += pr; wgs += pr*val;
    }
    {
      const float val = av[mt][3] + b2f(*(const u16*)(vb3 + mt*8192));
      const float pr = exp2f(al[mt][3]*sc); prs += pr; wgs += pr*val;
    }
    prs += __shfl_xor(prs, 16, 64); prs += __shfl_xor(prs, 32, 64);
    wgs += __shfl_xor(wgs, 16, 64); wgs += __shfl_xor(wgs, 32, 64);
    const float rv = wgs * __builtin_amdgcn_rcpf(prs);
    if (quad == 0)
      res[(gb + nbase + mt)*256 + fr + mrow] = f2b(rv);
  }
}

// ---------------- launcher ----------------
extern "C" void kernel_launch(void* const* d_in, const int* in_sizes, int n_in,
                              void* d_out, int out_size, void* d_ws, size_t ws_size,
                              hipStream_t stream){
  const float* xyz    = (const float*)d_in[0];
  const float* feat   = (const float*)d_in[1];
  const float* W_pre  = (const float*)d_in[2];
  const float* b_pre  = (const float*)d_in[3];
  const float* W_post = (const float*)d_in[4];
  const float* b_post = (const float*)d_in[5];
  const float* Wp1    = (const float*)d_in[6];
  const float* Wp2    = (const float*)d_in[7];
  const float* Wa1    = (const float*)d_in[8];
  const float* Wa2    = (const float*)d_in[9];
  const float* WQ     = (const float*)d_in[10];
  const float* WK     = (const float*)d_in[11];
  const float* WV     = (const float*)d_in[12];
  const float* Wproj  = (const float*)d_in[13];
  const float* g_dm   = (const float*)d_in[14];
  const float* b_dm   = (const float*)d_in[15];
  const float* g_dp   = (const float*)d_in[16];
  const float* b_dp   = (const float*)d_in[17];
  float* out = (float*)d_out;
  if (ws_size < WS_NEED) return;
  char* ws = (char*)d_ws;
  int* idxw   = (int*)(ws + OFF_IDX);
  u16* wqkvb  = (u16*)(ws + OFF_WQKV);
  u16* wa1b   = (u16*)(ws + OFF_WA1);
  u16* wa2b   = (u16*)(ws + OFF_WA2);
  u16* wp2b   = (u16*)(ws + OFF_WP2);
  u16* wprojb = (u16*)(ws + OFF_WPROJ);
  u16* wpostb = (u16*)(ws + OFF_WPOST);
  u16* mcombb = (u16*)(ws + OFF_MCOMB);
  u16* inp    = (u16*)(ws + OFF_INP);
  u16* lnqkv  = (u16*)(ws + OFF_LNQKV);
  u16* qab    = (u16*)(ws + OFF_QA);
  u16* kab    = (u16*)(ws + OFF_KA);
  u16* resb   = (u16*)(ws + OFF_RES);
  u16* wp1pk  = (u16*)(ws + OFF_WP1PK);

  // 1) merged prologue: kNN (blocks 0..1023, first) + weight converts + wp1 pack
  //    + mcomb + inp GEMM (blocks 1024..3392) -- independent roots, pipe overlap.
  prep_k<<<3393,256,0,stream>>>(xyz, feat, W_pre, b_pre, WQ, WK, WV, Wa1, Wa2, Wp2,
                                Wproj, W_post, Wp1,
                                wqkvb, wa1b, wa2b, wp2b, wprojb, wpostb,
                                wp1pk, mcombb, idxw, inp);
  // 2) q: qa = ln(inp@WQ.T)@Wa1.T ; k: ka = ...; v: lnv slice
  gemmlnqa_k<<<dim3(256,1,3),512,0,stream>>>(inp, wqkvb, wa1b, qab, kab, lnqkv, g_dm, b_dm);
  // 3) attention: 2048 blocks x 1024 threads, 8 queries/block
  attn_k<<<2048,1024,0,stream>>>(xyz,idxw,lnqkv,qab,kab,mcombb,wp2b,wa2b,wp1pk,resb);
  // 4) out = ln( ln(res@Wproj.T)@Wpost.T + b_post )*g+b + feat
  projpost_k<<<256,512,0,stream>>>(resb, wprojb, wpostb, b_post, g_dm, b_dm, g_dp, b_dp,
                                   feat, out);
}

// Round 13
// 373.255 us; speedup vs baseline: 1.1299x; 1.0035x over previous
//
#include <hip/hip_runtime.h>
#include <hip/hip_bf16.h>

typedef unsigned short u16;
typedef unsigned int   u32;
typedef __attribute__((ext_vector_type(8))) short bf16x8;
typedef __attribute__((ext_vector_type(4))) float f32x4;

#define MFMA16(a,b,c) __builtin_amdgcn_mfma_f32_16x16x32_bf16((a),(b),(c),0,0,0)

__device__ __forceinline__ float b2f(u32 h){ return __uint_as_float(h<<16); }
__device__ __forceinline__ u16 f2b(float f){
  u32 u = __float_as_uint(f);
  return (u16)((u + 0x7FFFu + ((u>>16)&1u))>>16);
}
// HW packed convert: v_cvt_pk_bf16_f32 (RNE)
__device__ __forceinline__ u32 pk2f(float a,float b){
  __hip_bfloat162 h = __float22bfloat162_rn(float2{a,b});
  return *reinterpret_cast<u32*>(&h);
}
__device__ __forceinline__ u32 umin32(u32 a,u32 b){ return a<b?a:b; }
__device__ __forceinline__ u32 umax32(u32 a,u32 b){ return a>b?a:b; }

// 16-lane row-sum on the VALU pipe via DPP row_ror
template<int CTRL>
__device__ __forceinline__ float dpp_add(float x){
  int t = __builtin_amdgcn_update_dpp(0, __float_as_int(x), CTRL, 0xF, 0xF, true);
  return x + __int_as_float(t);
}
__device__ __forceinline__ float rowsum16(float x){
  x = dpp_add<0x121>(x);
  x = dpp_add<0x122>(x);
  x = dpp_add<0x124>(x);
  x = dpp_add<0x128>(x);
  return x;
}

__device__ __forceinline__ void async_copy16(const void* g, void* l){
  __builtin_amdgcn_global_load_lds((const __attribute__((address_space(1))) u32*)g,
                                   (__attribute__((address_space(3))) u32*)l, 16, 0, 0);
}

// ---------------- workspace layout (bytes) ----------------
#define OFF_IDX    0ull
#define OFF_WQKV   3178496ull
#define OFF_WA1    3571712ull
#define OFF_WA2    3702784ull
#define OFF_WP2    3833856ull
#define OFF_WPROJ  3964928ull
#define OFF_WPOST  4096000ull
#define OFF_MCOMB  4128768ull
#define OFF_INP    4259840ull
#define OFF_LNQKV  37814272ull
#define OFF_QA     62980096ull
#define OFF_KA     71368704ull
#define OFF_RES    79757312ull
#define OFF_D1     88145920ull
#define WS_NEED    104923136ull
#define OFF_WP1PK  OFF_D1

// ---------------- kNN insertion: a[j] = med3(a[j-1], key, a[j]) ----------------
// Given sorted a[0..15] ascending, min(max(a[j-1],key),a[j]) == median3 of the
// three. v_med3_u32 replaces the 2-op min/max pair -> 16 instr per candidate.
__device__ __forceinline__ void ins16(u32 (&a)[16], u32 key){
  #pragma unroll
  for (int j = 15; j >= 1; --j){
    u32 r;
    asm("v_med3_u32 %0, %1, %2, %3" : "=v"(r) : "v"(a[j-1]), "v"(key), "v"(a[j]));
    a[j] = r;
  }
  a[0] = umin32(a[0], key);
}

__device__ __forceinline__ float dist2(float ax,float ay,float az,float bx,float by,float bz){
  const float dx = ax-bx, dy = ay-by, dz = az-bz;
  return __fmaf_rn(dx,dx, __fmaf_rn(dy,dy, dz*dz));
}

// ---------------- merged prep: kNN (blocks 0..1023, dispatched FIRST) +
//                  weight converts / wp1 pack / mcomb / inp GEMM (blocks 1024..3392)
__global__ __launch_bounds__(256,2) void prep_k(
    const float* __restrict__ xyz, const float* __restrict__ feat,
    const float* __restrict__ wpre, const float* __restrict__ bpre,
    const float* __restrict__ wq, const float* __restrict__ wk, const float* __restrict__ wv,
    const float* __restrict__ wa1, const float* __restrict__ wa2, const float* __restrict__ wp2,
    const float* __restrict__ wproj, const float* __restrict__ wpost,
    const float* __restrict__ wp1,
    u16* __restrict__ dwqkv, u16* __restrict__ dwa1, u16* __restrict__ dwa2,
    u16* __restrict__ dwp2, u16* __restrict__ dwproj, u16* __restrict__ dwpost,
    u16* __restrict__ dwp1pk, u16* __restrict__ dmcomb,
    int* __restrict__ idxout, u16* __restrict__ dinp){
  __shared__ __attribute__((aligned(16))) char smem[51200];
  const int bid0 = blockIdx.x, tid = threadIdx.x;
  if (bid0 < 1024){
    // ---------------- kNN role ----------------
    float* sx = (float*)smem;              // [16][260]
    float* sy = sx + 4160;
    float* sz = sy + 4160;                 // ends at byte 49920
    int* lcnt   = (int*)(smem + 49920);
    int* tcnt   = (int*)(smem + 49984);
    u32* tbuf   = (u32*)(smem + 50048);
    int* tiebuf = (int*)(smem + 50112);    // 1024 B -> 51136
    const int b  = bid0 >> 8;
    const int n0 = (bid0 & 255) << 4;
    const float* base = xyz + (size_t)b*12288;
    #pragma unroll
    for (int i = 0; i < 12; ++i){
      const float4 v = *(const float4*)(base + tid*48 + i*4);
      const float vv[4] = {v.x, v.y, v.z, v.w};
      #pragma unroll
      for (int j = 0; j < 4; ++j){
        const int e = i*4 + j;
        const int c = e % 3;
        const int m = tid*16 + e/3;
        float* arr = (c==0)?sx:((c==1)?sy:sz);
        arr[(m>>8)*260 + (m&255)] = vv[j];
      }
    }
    if (tid < 16){ lcnt[tid] = 0; tcnt[tid] = 0; }
    __syncthreads();
    const int qi = tid >> 4, p = tid & 15;
    const int n = n0 + qi;
    const float qx = sx[(n>>8)*260 + (n&255)];
    const float qy = sy[(n>>8)*260 + (n&255)];
    const float qz = sz[(n>>8)*260 + (n&255)];
    u32 a[16];
    #pragma unroll
    for (int j = 0; j < 16; ++j) a[j] = 0xFFFFFFFFu;
    const float* px = sx + p*260;
    const float* py = sy + p*260;
    const float* pz = sz + p*260;
    #pragma unroll 2
    for (int i4 = 0; i4 < 64; ++i4){
      const float4 x4 = *(const float4*)(px + i4*4);
      const float4 y4 = *(const float4*)(py + i4*4);
      const float4 z4 = *(const float4*)(pz + i4*4);
      ins16(a, __float_as_uint(dist2(x4.x,y4.x,z4.x,qx,qy,qz)));
      ins16(a, __float_as_uint(dist2(x4.y,y4.y,z4.y,qx,qy,qz)));
      ins16(a, __float_as_uint(dist2(x4.z,y4.z,z4.z,qx,qy,qz)));
      ins16(a, __float_as_uint(dist2(x4.w,y4.w,z4.w,qx,qy,qz)));
    }
    #pragma unroll
    for (int s = 8; s >= 1; s >>= 1){
      u32 o[16];
      #pragma unroll
      for (int j = 0; j < 16; ++j) o[j] = __shfl_down(a[j], (unsigned)s, 64);
      if (p < s){
        #pragma unroll
        for (int j = 0; j < 16; ++j) ins16(a, o[j]);
      }
    }
    if (p == 0) tbuf[qi] = a[15];
    __syncthreads();
    const u32 T = tbuf[qi];
    int* orow = idxout + ((size_t)(b<<12)+n)*16;
    const int gbase = p*256;
    for (int i4 = 0; i4 < 64; ++i4){
      const float4 x4 = *(const float4*)(px + i4*4);
      const float4 y4 = *(const float4*)(py + i4*4);
      const float4 z4 = *(const float4*)(pz + i4*4);
      const float xv[4] = {x4.x,x4.y,x4.z,x4.w};
      const float yv[4] = {y4.x,y4.y,y4.z,y4.w};
      const float zv[4] = {z4.x,z4.y,z4.z,z4.w};
      #pragma unroll
      for (int j = 0; j < 4; ++j){
        const float d2 = dist2(xv[j],yv[j],zv[j],qx,qy,qz);
        const u32 kb = __float_as_uint(d2);
        if (kb < T){
          const int pos = atomicAdd(&lcnt[qi],1);
          if (pos < 16) orow[pos] = gbase + i4*4 + j;
        } else if (kb == T){
          const int t = atomicAdd(&tcnt[qi],1);
          if (t < 16) tiebuf[qi*16+t] = gbase + i4*4 + j;
        }
      }
    }
    __syncthreads();
    if (p == 0){
      int L = lcnt[qi]; if (L > 16) L = 16;
      int tc = tcnt[qi]; if (tc > 16) tc = 16;
      const int need = 16 - L;
      for (int r = 0; r < need; ++r){
        int best = 0x7FFFFFFF, bj = -1;
        for (int j = 0; j < tc; ++j){
          const int v = tiebuf[qi*16+j];
          if (v < best){ best = v; bj = j; }
        }
        if (bj >= 0){ tiebuf[qi*16+bj] = 0x7FFFFFFF; orow[L+r] = best; }
        else orow[L+r] = n;
      }
    }
    return;
  }
  const int bid = bid0 - 1024;   // 0..2368
  if (bid < 1856){
    int id = bid*256 + tid;
    const float* s; u16* d; int off;
    if      (id <  65536){ s=wq;    d=dwqkv;        off=id; }
    else if (id < 131072){ s=wk;    d=dwqkv+65536;  off=id-65536; }
    else if (id < 196608){ s=wv;    d=dwqkv+131072; off=id-131072; }
    else if (id < 262144){ s=wa1;   d=dwa1;         off=id-196608; }
    else if (id < 327680){ s=wa2;   d=dwa2;         off=id-262144; }
    else if (id < 393216){ s=wp2;   d=dwp2;         off=id-327680; }
    else if (id < 458752){ s=wproj; d=dwproj;       off=id-393216; }
    else                 { s=wpost; d=dwpost;       off=id-458752; }
    d[off] = f2b(s[off]);
  } else if (bid == 1856){
    const int h = tid;
    const float w0 = wp1[h*3], w1 = wp1[h*3+1], w2 = wp1[h*3+2];
    uint4 a; a.x = pk2f(w0,w1); a.y = pk2f(w2,0.f); a.z = 0u; a.w = 0u;
    uint4 z; z.x = z.y = z.z = z.w = 0u;
    *(uint4*)&dwp1pk[h*32]    = a;
    *(uint4*)&dwp1pk[h*32+8]  = z;
    *(uint4*)&dwp1pk[h*32+16] = z;
    *(uint4*)&dwp1pk[h*32+24] = z;
  } else if (bid < 2113){
    const int f = bid - 1857, h = tid;
    float acc = 0.f;
    #pragma unroll 4
    for (int j = 0; j < 256; ++j) acc = __fmaf_rn(wa1[f*256+j], wp2[j*256+h], acc);
    dmcomb[f*256+h] = f2b(acc);
  } else {
    // ---- inp = feat @ W_pre.T + b_pre (K=64), 128x128 tile
    u16* As = (u16*)smem;            // [128][72]
    u16* Bs = (u16*)smem + 9216;     // [128][72]
    const int tb = bid - 2113;
    const int mb = tb >> 1, nb = tb & 1;
    #pragma unroll
    for (int i = 0; i < 32; ++i){
      const int e = i*256 + tid;
      const int row = e >> 6, k = e & 63;
      As[row*72+k] = f2b(feat[(size_t)(mb*128)*64 + e]);
      Bs[row*72+k] = f2b(wpre[(size_t)(nb*128)*64 + e]);
    }
    __syncthreads();
    const int lane = tid & 63, w = tid >> 6;
    const int mrow = lane & 15, quad = lane >> 4;
    const int wr = (w&1)*64, wc = (w>>1)*64;
    f32x4 acc[4][4];
    #pragma unroll
    for (int i=0;i<4;++i)
      #pragma unroll
      for (int j=0;j<4;++j)
        #pragma unroll
        for (int r=0;r<4;++r) acc[i][j][r] = 0.f;
    #pragma unroll
    for (int ks = 0; ks < 2; ++ks){
      const int koff = ks*32 + quad*8;
      bf16x8 af[4], bf[4];
      #pragma unroll
      for (int rt=0;rt<4;++rt) af[rt] = *(const bf16x8*)&As[(wr+rt*16+mrow)*72 + koff];
      #pragma unroll
      for (int ct=0;ct<4;++ct) bf[ct] = *(const bf16x8*)&Bs[(wc+ct*16+mrow)*72 + koff];
      #pragma unroll
      for (int rt=0;rt<4;++rt)
        #pragma unroll
        for (int ct=0;ct<4;++ct) acc[rt][ct] = MFMA16(af[rt], bf[ct], acc[rt][ct]);
    }
    #pragma unroll
    for (int rt=0;rt<4;++rt)
      #pragma unroll
      for (int ct=0;ct<4;++ct){
        const size_t row0 = (size_t)mb*128 + wr + rt*16 + quad*4;
        const int col = nb*128 + wc + ct*16 + mrow;
        const float bv = bpre[col];
        #pragma unroll
        for (int r=0;r<4;++r) dinp[(row0+r)*256 + col] = f2b(acc[rt][ct][r] + bv);
      }
  }
}

// ---------------- fused GEMM+LN (+second GEMM for qa/ka): 64-row tiles ----------------
// v2: BK 32 -> 64. 16 -> 8 total k-steps; each barrier drain now amortizes 16
// MFMAs/wave instead of 8 (these kernels are barrier-drain-bound: per-step MFMA
// work ~40cy vs ~300cy vmcnt(0) drain). LDS 74.3KB -> still 2 blocks/CU.
// z=0: qa = ln(inp@WQ.T) @ Wa1.T   z=1: ka = ln(inp@WK.T) @ Wa1.T
// z=2: lnv slice = ln(inp@WV.T)
#define LNP 264
__global__ __launch_bounds__(512,2) void gemmlnqa_k(
    const u16* __restrict__ inp, const u16* __restrict__ wqkv, const u16* __restrict__ wa1,
    u16* __restrict__ qa, u16* __restrict__ ka, u16* __restrict__ lnqkv,
    const float* __restrict__ g, const float* __restrict__ bta){
  __shared__ __attribute__((aligned(16))) u16 As[64*64];      // 8 KB
  __shared__ __attribute__((aligned(16))) u16 Bs[256*64];     // 32 KB
  __shared__ __attribute__((aligned(16))) u16 lnbuf[64*LNP];  // 33.8 KB
  __shared__ float sS[64], sSS[64];
  const int z = blockIdx.z;
  const u16* wsel = wqkv + z*65536;
  const int tid = threadIdx.x, lane = tid & 63, w = tid >> 6;
  const int mrow = lane & 15, quad = lane >> 4;
  const size_t mbase = (size_t)blockIdx.x*64;
  const int wr = (w&1)*32, wc = (w>>1)*64;
  if (tid < 64){ sS[tid] = 0.f; sSS[tid] = 0.f; }
  f32x4 acc[2][4];
  #pragma unroll
  for (int i=0;i<2;++i)
    #pragma unroll
    for (int j=0;j<4;++j)
      #pragma unroll
      for (int r=0;r<4;++r) acc[i][j][r] = 0.f;
  const int sr8 = tid >> 3, sk8 = (tid & 7)*8;
  // ---- phase 1: X = inp(64 rows) @ wsel.T  (BK=64, 4 k-steps)
  for (int k0 = 0; k0 < 256; k0 += 64){
    __syncthreads();
    async_copy16(inp + (mbase + sr8)*256 + k0 + sk8, &As[w*512]);
    #pragma unroll
    for (int i=0;i<4;++i)
      async_copy16(wsel + (size_t)(i*64 + sr8)*256 + k0 + sk8, &Bs[i*4096 + w*512]);
    __syncthreads();
    #pragma unroll
    for (int ks2=0; ks2<2; ++ks2){
      const int koff = ks2*32 + quad*8;
      bf16x8 af[2], bf[4];
      #pragma unroll
      for (int rt=0;rt<2;++rt) af[rt] = *(const bf16x8*)&As[(wr+rt*16+mrow)*64 + koff];
      #pragma unroll
      for (int ct=0;ct<4;++ct) bf[ct] = *(const bf16x8*)&Bs[(wc+ct*16+mrow)*64 + koff];
      #pragma unroll
      for (int rt=0;rt<2;++rt)
        #pragma unroll
        for (int ct=0;ct<4;++ct) acc[rt][ct] = MFMA16(af[rt], bf[ct], acc[rt][ct]);
    }
  }
  // row stats (f32) across 4 col-waves
  #pragma unroll
  for (int rt=0;rt<2;++rt)
    #pragma unroll
    for (int r=0;r<4;++r){
      float s  = acc[rt][0][r]+acc[rt][1][r]+acc[rt][2][r]+acc[rt][3][r];
      float ss = acc[rt][0][r]*acc[rt][0][r]+acc[rt][1][r]*acc[rt][1][r]
               + acc[rt][2][r]*acc[rt][2][r]+acc[rt][3][r]*acc[rt][3][r];
      s  = rowsum16(s);
      ss = rowsum16(ss);
      if (mrow == 0){
        const int row = wr + rt*16 + quad*4 + r;
        atomicAdd(&sS[row],  s);
        atomicAdd(&sSS[row], ss);
      }
    }
  __syncthreads();
  // apply LN
  #pragma unroll
  for (int ct=0;ct<4;++ct){
    const int col = wc + ct*16 + mrow;
    const float gv = g[col], bv = bta[col];
    #pragma unroll
    for (int rt=0;rt<2;++rt)
      #pragma unroll
      for (int r=0;r<4;++r){
        const int row = wr + rt*16 + quad*4 + r;
        const float mu = sS[row]*(1.f/256.f);
        const float var = sSS[row]*(1.f/256.f) - mu*mu;
        const float rs = rsqrtf(var + 1e-5f);
        const u16 hv = f2b((acc[rt][ct][r]-mu)*rs*gv + bv);
        if (z == 2) lnqkv[(mbase+row)*768 + 512 + col] = hv;
        else        lnbuf[row*LNP + col] = hv;
      }
  }
  if (z == 2) return;
  // ---- phase 2: out = lnbuf @ Wa1.T  (BK=64, 4 k-steps, Bs restaged)
  u16* outp = (z == 0) ? qa : ka;
  f32x4 ac2[2][4];
  #pragma unroll
  for (int i=0;i<2;++i)
    #pragma unroll
    for (int j=0;j<4;++j)
      #pragma unroll
      for (int r=0;r<4;++r) ac2[i][j][r] = 0.f;
  for (int k0 = 0; k0 < 256; k0 += 64){
    __syncthreads();
    #pragma unroll
    for (int i=0;i<4;++i)
      async_copy16(wa1 + (size_t)(i*64 + sr8)*256 + k0 + sk8, &Bs[i*4096 + w*512]);
    __syncthreads();
    #pragma unroll
    for (int ks2=0; ks2<2; ++ks2){
      const int koffB = ks2*32 + quad*8;
      const int koffA = k0 + koffB;
      bf16x8 af[2], bf[4];
      #pragma unroll
      for (int rt=0;rt<2;++rt) af[rt] = *(const bf16x8*)&lnbuf[(wr+rt*16+mrow)*LNP + koffA];
      #pragma unroll
      for (int ct=0;ct<4;++ct) bf[ct] = *(const bf16x8*)&Bs[(wc+ct*16+mrow)*64 + koffB];
      #pragma unroll
      for (int rt=0;rt<2;++rt)
        #pragma unroll
        for (int ct=0;ct<4;++ct) ac2[rt][ct] = MFMA16(af[rt], bf[ct], ac2[rt][ct]);
    }
  }
  #pragma unroll
  for (int rt=0;rt<2;++rt)
    #pragma unroll
    for (int ct=0;ct<4;++ct){
      const size_t row0 = mbase + wr + rt*16 + quad*4;
      const int col = wc + ct*16 + mrow;
      #pragma unroll
      for (int r=0;r<4;++r) outp[(row0+r)*256 + col] = f2b(ac2[rt][ct][r]);
    }
}

// ---------------- fused: out = ln( ln(res@Wproj.T) @ Wpost.T + bpost )*g+b + feat ----------------
// v2: BK 32 -> 64 (same rationale as gemmlnqa). LDS 74.8KB -> 2 blocks/CU.
__global__ __launch_bounds__(512,2) void projpost_k(
    const u16* __restrict__ res, const u16* __restrict__ wproj, const u16* __restrict__ wpost,
    const float* __restrict__ bpost,
    const float* __restrict__ g_dm, const float* __restrict__ b_dm,
    const float* __restrict__ g_dp, const float* __restrict__ b_dp,
    const float* __restrict__ feat, float* __restrict__ out){
  __shared__ __attribute__((aligned(16))) u16 As[64*64];      // 8 KB
  __shared__ __attribute__((aligned(16))) u16 Bs[256*64];     // 32 KB
  __shared__ __attribute__((aligned(16))) u16 lnbuf[64*LNP];
  __shared__ float sS[64], sSS[64], sS2[64], sSS2[64];
  const int tid = threadIdx.x, lane = tid & 63, w = tid >> 6;
  const int mrow = lane & 15, quad = lane >> 4;
  const size_t mbase = (size_t)blockIdx.x*64;
  const int wr = (w&1)*32, wc = (w>>1)*64;
  if (tid < 64){ sS[tid]=0.f; sSS[tid]=0.f; sS2[tid]=0.f; sSS2[tid]=0.f; }
  f32x4 acc[2][4];
  #pragma unroll
  for (int i=0;i<2;++i)
    #pragma unroll
    for (int j=0;j<4;++j)
      #pragma unroll
      for (int r=0;r<4;++r) acc[i][j][r] = 0.f;
  const int sr8 = tid >> 3, sk8 = (tid & 7)*8;
  for (int k0 = 0; k0 < 256; k0 += 64){
    __syncthreads();
    async_copy16(res + (mbase + sr8)*256 + k0 + sk8, &As[w*512]);
    #pragma unroll
    for (int i=0;i<4;++i)
      async_copy16(wproj + (size_t)(i*64 + sr8)*256 + k0 + sk8, &Bs[i*4096 + w*512]);
    __syncthreads();
    #pragma unroll
    for (int ks2=0; ks2<2; ++ks2){
      const int koff = ks2*32 + quad*8;
      bf16x8 af[2], bf[4];
      #pragma unroll
      for (int rt=0;rt<2;++rt) af[rt] = *(const bf16x8*)&As[(wr+rt*16+mrow)*64 + koff];
      #pragma unroll
      for (int ct=0;ct<4;++ct) bf[ct] = *(const bf16x8*)&Bs[(wc+ct*16+mrow)*64 + koff];
      #pragma unroll
      for (int rt=0;rt<2;++rt)
        #pragma unroll
        for (int ct=0;ct<4;++ct) acc[rt][ct] = MFMA16(af[rt], bf[ct], acc[rt][ct]);
    }
  }
  #pragma unroll
  for (int rt=0;rt<2;++rt)
    #pragma unroll
    for (int r=0;r<4;++r){
      float s  = acc[rt][0][r]+acc[rt][1][r]+acc[rt][2][r]+acc[rt][3][r];
      float ss = acc[rt][0][r]*acc[rt][0][r]+acc[rt][1][r]*acc[rt][1][r]
               + acc[rt][2][r]*acc[rt][2][r]+acc[rt][3][r]*acc[rt][3][r];
      s  = rowsum16(s);
      ss = rowsum16(ss);
      if (mrow == 0){
        const int row = wr + rt*16 + quad*4 + r;
        atomicAdd(&sS[row],  s);
        atomicAdd(&sSS[row], ss);
      }
    }
  __syncthreads();
  #pragma unroll
  for (int ct=0;ct<4;++ct){
    const int col = wc + ct*16 + mrow;
    const float gv = g_dm[col], bv = b_dm[col];
    #pragma unroll
    for (int rt=0;rt<2;++rt)
      #pragma unroll
      for (int r=0;r<4;++r){
        const int row = wr + rt*16 + quad*4 + r;
        const float mu = sS[row]*(1.f/256.f);
        const float var = sSS[row]*(1.f/256.f) - mu*mu;
        const float rs = rsqrtf(var + 1e-5f);
        lnbuf[row*LNP + col] = f2b((acc[rt][ct][r]-mu)*rs*gv + bv);
      }
  }
  // ---- phase 2: d = lnbuf @ Wpost.T + bpost  (BK=64, 4 k-steps); wave = 16 rows x 32 cols
  const int wr2 = (w & 3)*16, wc2 = (w >> 2)*32;
  f32x4 ac2[2];
  #pragma unroll
  for (int j=0;j<2;++j)
    #pragma unroll
    for (int r=0;r<4;++r) ac2[j][r] = 0.f;
  for (int k0 = 0; k0 < 256; k0 += 64){
    __syncthreads();
    async_copy16(wpost + (size_t)sr8*256 + k0 + sk8, &Bs[w*512]);
    __syncthreads();
    #pragma unroll
    for (int ks2=0; ks2<2; ++ks2){
      const int koffB = ks2*32 + quad*8;
      bf16x8 af, bf[2];
      af = *(const bf16x8*)&lnbuf[(wr2+mrow)*LNP + k0 + koffB];
      #pragma unroll
      for (int ct=0;ct<2;++ct) bf[ct] = *(const bf16x8*)&Bs[(wc2+ct*16+mrow)*64 + koffB];
      #pragma unroll
      for (int ct=0;ct<2;++ct) ac2[ct] = MFMA16(af, bf[ct], ac2[ct]);
    }
  }
  #pragma unroll
  for (int ct=0;ct<2;++ct){
    const float bv = bpost[wc2 + ct*16 + mrow];
    #pragma unroll
    for (int r=0;r<4;++r) ac2[ct][r] += bv;
  }
  #pragma unroll
  for (int r=0;r<4;++r){
    float s  = ac2[0][r] + ac2[1][r];
    float ss = ac2[0][r]*ac2[0][r] + ac2[1][r]*ac2[1][r];
    s  = rowsum16(s);
    ss = rowsum16(ss);
    if (mrow == 0){
      const int row = wr2 + quad*4 + r;
      atomicAdd(&sS2[row],  s);
      atomicAdd(&sSS2[row], ss);
    }
  }
  __syncthreads();
  #pragma unroll
  for (int ct=0;ct<2;++ct){
    const int col = wc2 + ct*16 + mrow;
    const float gv = g_dp[col], bv = b_dp[col];
    #pragma unroll
    for (int r=0;r<4;++r){
      const int row = wr2 + quad*4 + r;
      const float mu = sS2[row]*(1.f/64.f);
      const float var = sSS2[row]*(1.f/64.f) - mu*mu;
      const float rs = rsqrtf(var + 1e-5f);
      const size_t grow = mbase + row;
      out[grow*64 + col] = (ac2[ct][r]-mu)*rs*gv + bv + feat[grow*64 + col];
    }
  }
}

// ---------------- fused per-neighbor attention kernel (v18, unchanged) ----------------
#define RELP 40
// swizzled address (kept for the tid<128 prologue / reference)
__device__ __forceinline__ u16* swzp(u16* p, int row, int cb){
  return (u16*)((char*)p + row*512 + (cb ^ ((row & 7) << 4)));
}
__global__ __launch_bounds__(1024,4) void attn_k(
    const float* __restrict__ xyz, const int* __restrict__ idxb,
    const u16* __restrict__ lnqkv, const u16* __restrict__ qa, const u16* __restrict__ ka,
    const u16* __restrict__ mcomb, const u16* __restrict__ wp2, const u16* __restrict__ wa2,
    const u16* __restrict__ wp1pk, u16* __restrict__ res){
  __shared__ __attribute__((aligned(16))) u16 h1buf[128*256]; // h1, later v rows (swizzled) 64KB
  __shared__ __attribute__((aligned(16))) u16 h2buf[128*256]; // ka-gather, then h2 (swizzled) 64KB
  __shared__ __attribute__((aligned(16))) u16 qbuf[8*256];    // qa rows (LINEAR) 4KB
  __shared__ __attribute__((aligned(16))) u16 srel[128*RELP]; // 10KB
  __shared__ int sidx[128];
  const int tid = threadIdx.x;
  const int b = blockIdx.x >> 9;
  const int nbase = (blockIdx.x & 511) << 3;
  const size_t gb = (size_t)b << 12;
  if (tid < 128){
    const int m = tid;
    const int im = idxb[(gb + nbase + (m>>4))*16 + (m&15)] & 4095;
    sidx[m] = im;
    const int nn = nbase + (m>>4);
    const float* pq = xyz + (gb+nn)*3;
    const float* pm = xyz + (gb+im)*3;
    const float rx = pq[0]-pm[0], ry = pq[1]-pm[1], rz = pq[2]-pm[2];
    uint4 a; a.x = pk2f(rx,ry); a.y = pk2f(rz,0.f); a.z = 0u; a.w = 0u;
    uint4 z; z.x = z.y = z.z = z.w = 0u;
    *(uint4*)&srel[m*RELP]    = a;
    *(uint4*)&srel[m*RELP+8]  = z;
    *(uint4*)&srel[m*RELP+16] = z;
    *(uint4*)&srel[m*RELP+24] = z;
  }
  __syncthreads();
  const int lane = tid & 63, w = tid >> 6;       // w in 0..15
  const int mrow = lane & 15, quad = lane >> 4;
  const int fr = w << 4;                          // 16 f-rows per wave
  // ---- hoisted swizzled-address bases (all mt/ks terms become immediates)
  const int swc      = (mrow & 7) << 4;                   // row-XOR constant (bytes)
  const int cbst     = (2*(fr + quad*4)) ^ swc;           // C-frag col-block, swizzled
  char* h1st = (char*)h1buf + mrow*512 + cbst;            // + mt*8192 (h1 store)
  char* h2st = (char*)h2buf + mrow*512 + cbst;            // + mt*8192 (pack RMW)
  const int quadoff  = (quad*16) ^ (swc & 0x30);
  const char* h1rd = (const char*)h1buf + mrow*512 + quadoff;  // + ksx + m8*8192
  const char* h2rd = (const char*)h2buf + mrow*512 + quadoff;
  const int ksxc = swc & 0x40;
  // ---- h1 = relu(rel @ Wp1.T): wave covers h-rows [fr,fr+16) x 128 pairs
  {
    bf16x8 aW = *(const bf16x8*)&wp1pk[(fr+mrow)*32 + quad*8];
    #pragma unroll
    for (int mt=0;mt<8;++mt){
      bf16x8 bR = *(const bf16x8*)&srel[(mt*16+mrow)*RELP + quad*8];
      f32x4 hz;
      #pragma unroll
      for (int r=0;r<4;++r) hz[r]=0.f;
      hz = MFMA16(aW, bR, hz);
      float h0 = hz[0]>0.f?hz[0]:0.f, h1v = hz[1]>0.f?hz[1]:0.f;
      float h2v = hz[2]>0.f?hz[2]:0.f, h3 = hz[3]>0.f?hz[3]:0.f;
      uint2 o; o.x = pk2f(h0,h1v); o.y = pk2f(h2v,h3);
      *(uint2*)(h1st + mt*8192) = o;
    }
  }
  __syncthreads();
  // ---- pre-gather: ka rows -> h2buf (all waves), qa rows -> qbuf (waves 0..3, linear).
  // Issued before loop1; the barrier after loop1 drains them (vmcnt(0)).
  {
    #pragma unroll
    for (int i = 0; i < 4; ++i){
      const int row = w*8 + i*2 + (lane>>5);
      const int c   = ((lane&31)*8) ^ ((row & 7) << 3);   // u16 elems, inverse swizzle
      async_copy16(ka + (gb + (size_t)sidx[row])*256 + c,
                   &h2buf[w*2048 + i*512]);
    }
    if (w < 4){
      const int row = w*2 + (lane>>5);
      async_copy16(qa + (gb + nbase + row)*256 + (lane&31)*8, &qbuf[w*512]);
    }
  }
  // ---- loop1: at = mcomb @ h1 ; av = h1 @ wp2.T  (K = 256 over h)
  f32x4 at[8], av[8];
  #pragma unroll
  for (int j=0;j<8;++j)
    #pragma unroll
    for (int r=0;r<4;++r){ at[j][r]=0.f; av[j][r]=0.f; }
  #pragma unroll 1
  for (int ks = 0; ks < 8; ++ks){
    const int koff = ks*32 + quad*8;
    bf16x8 aM = *(const bf16x8*)&mcomb[(fr+mrow)*256 + koff];
    bf16x8 aP = *(const bf16x8*)&wp2  [(fr+mrow)*256 + koff];
    const char* hb = h1rd + ((ks*64) ^ ksxc);
    #pragma unroll
    for (int mh=0; mh<2; ++mh){
      bf16x8 bH[4];
      #pragma unroll
      for (int mi=0;mi<4;++mi) bH[mi] = *(const bf16x8*)(hb + (mh*4+mi)*8192);
      #pragma unroll
      for (int mi=0;mi<4;++mi){
        at[mh*4+mi] = MFMA16(aM, bH[mi], at[mh*4+mi]);
        av[mh*4+mi] = MFMA16(bH[mi], aP, av[mh*4+mi]);
      }
    }
  }
  __syncthreads();   // drains ka/qa gathers; h2buf(ka)+qbuf now visible to all
  // ---- pack: h2 = relu(at + qa - ka) -> bf16 (swizzled, overwrites ka in place)
  #pragma unroll
  for (int mt=0;mt<8;++mt){
    u16* addr = (u16*)(h2st + mt*8192);
    const uint2 kv = *(const uint2*)addr;
    const uint2 qv = *(const uint2*)&qbuf[mt*256 + fr + quad*4];
    float t0 = at[mt][0] + b2f(qv.x&0xffff) - b2f(kv.x&0xffff);
    float t1 = at[mt][1] + b2f(qv.x>>16)    - b2f(kv.x>>16);
    float t2 = at[mt][2] + b2f(qv.y&0xffff) - b2f(kv.y&0xffff);
    float t3 = at[mt][3] + b2f(qv.y>>16)    - b2f(kv.y>>16);
    t0 = t0>0.f?t0:0.f; t1 = t1>0.f?t1:0.f; t2 = t2>0.f?t2:0.f; t3 = t3>0.f?t3:0.f;
    uint2 o; o.x = pk2f(t0,t1); o.y = pk2f(t2,t3);
    *(uint2*)addr = o;
  }
  __syncthreads();
  // ---- async v-gather: linear LDS dest, inverse-swizzled global source (hidden under loop2)
  {
    #pragma unroll
    for (int i = 0; i < 4; ++i){
      const int row = w*8 + i*2 + (lane>>5);
      const int c   = ((lane&31)*8) ^ ((row & 7) << 3);
      async_copy16(lnqkv + (gb + (size_t)sidx[row])*768 + 512 + c,
                   &h1buf[w*2048 + i*512]);
    }
  }
  // ---- loop2: al = h2 @ wa2.T
  f32x4 al[8];
  #pragma unroll
  for (int j=0;j<8;++j)
    #pragma unroll
    for (int r=0;r<4;++r) al[j][r]=0.f;
  #pragma unroll 1
  for (int ks = 0; ks < 8; ++ks){
    const int koff = ks*32 + quad*8;
    bf16x8 aW = *(const bf16x8*)&wa2[(fr+mrow)*256 + koff];
    const char* hb = h2rd + ((ks*64) ^ ksxc);
    #pragma unroll
    for (int mh=0; mh<2; ++mh){
      bf16x8 bH[4];
      #pragma unroll
      for (int mi=0;mi<4;++mi) bH[mi] = *(const bf16x8*)(hb + (mh*4+mi)*8192);
      #pragma unroll
      for (int mi=0;mi<4;++mi) al[mh*4+mi] = MFMA16(bH[mi], aW, al[mh*4+mi]);
    }
  }
  __syncthreads();
  // ---- softmax over the 16 neighbors + weighted reduce of (v + pos)
  const float sc = 0.0901684f;   // log2(e)/sqrt(256)
  // hoisted v-read bases: addr(mt,r) = vb_r + mt*8192 (imm)
  const char* vb0 = (const char*)h1buf + (quad*4+0)*512 + ((2*(fr+mrow)) ^ ((((quad*4)+0)&7)<<4));
  const char* vb1 = (const char*)h1buf + (quad*4+1)*512 + ((2*(fr+mrow)) ^ ((((quad*4)+1)&7)<<4));
  const char* vb2 = (const char*)h1buf + (quad*4+2)*512 + ((2*(fr+mrow)) ^ ((((quad*4)+2)&7)<<4));
  const char* vb3 = (const char*)h1buf + (quad*4+3)*512 + ((2*(fr+mrow)) ^ ((((quad*4)+3)&7)<<4));
  #pragma unroll
  for (int mt=0;mt<8;++mt){
    float prs = 0.f, wgs = 0.f;
    {
      const float val = av[mt][0] + b2f(*(const u16*)(vb0 + mt*8192));
      const float pr = exp2f(al[mt][0]*sc); prs += pr; wgs += pr*val;
    }
    {
      const float val = av[mt][1] + b2f(*(const u16*)(vb1 + mt*8192));
      const float pr = exp2f(al[mt][1]*sc); prs += pr; wgs += pr*val;
    }
    {
      const float val = av[mt][2] + b2f(*(const u16*)(vb2 + mt*8192));
      const float pr = exp2f(al[mt][2]*sc); prs += pr; wgs += pr*val;
    }
    {
      const float val = av[mt][3] + b2f(*(const u16*)(vb3 + mt*8192));
      const float pr = exp2f(al[mt][3]*sc); prs += pr; wgs += pr*val;
    }
    prs += __shfl_xor(prs, 16, 64); prs += __shfl_xor(prs, 32, 64);
    wgs += __shfl_xor(wgs, 16, 64); wgs += __shfl_xor(wgs, 32, 64);
    const float rv = wgs * __builtin_amdgcn_rcpf(prs);
    if (quad == 0)
      res[(gb + nbase + mt)*256 + fr + mrow] = f2b(rv);
  }
}

// ---------------- launcher ----------------
extern "C" void kernel_launch(void* const* d_in, const int* in_sizes, int n_in,
                              void* d_out, int out_size, void* d_ws, size_t ws_size,
                              hipStream_t stream){
  const float* xyz    = (const float*)d_in[0];
  const float* feat   = (const float*)d_in[1];
  const float* W_pre  = (const float*)d_in[2];
  const float* b_pre  = (const float*)d_in[3];
  const float* W_post = (const float*)d_in[4];
  const float* b_post = (const float*)d_in[5];
  const float* Wp1    = (const float*)d_in[6];
  const float* Wp2    = (const float*)d_in[7];
  const float* Wa1    = (const float*)d_in[8];
  const float* Wa2    = (const float*)d_in[9];
  const float* WQ     = (const float*)d_in[10];
  const float* WK     = (const float*)d_in[11];
  const float* WV     = (const float*)d_in[12];
  const float* Wproj  = (const float*)d_in[13];
  const float* g_dm   = (const float*)d_in[14];
  const float* b_dm   = (const float*)d_in[15];
  const float* g_dp   = (const float*)d_in[16];
  const float* b_dp   = (const float*)d_in[17];
  float* out = (float*)d_out;
  if (ws_size < WS_NEED) return;
  char* ws = (char*)d_ws;
  int* idxw   = (int*)(ws + OFF_IDX);
  u16* wqkvb  = (u16*)(ws + OFF_WQKV);
  u16* wa1b   = (u16*)(ws + OFF_WA1);
  u16* wa2b   = (u16*)(ws + OFF_WA2);
  u16* wp2b   = (u16*)(ws + OFF_WP2);
  u16* wprojb = (u16*)(ws + OFF_WPROJ);
  u16* wpostb = (u16*)(ws + OFF_WPOST);
  u16* mcombb = (u16*)(ws + OFF_MCOMB);
  u16* inp    = (u16*)(ws + OFF_INP);
  u16* lnqkv  = (u16*)(ws + OFF_LNQKV);
  u16* qab    = (u16*)(ws + OFF_QA);
  u16* kab    = (u16*)(ws + OFF_KA);
  u16* resb   = (u16*)(ws + OFF_RES);
  u16* wp1pk  = (u16*)(ws + OFF_WP1PK);

  // 1) merged prologue: kNN (blocks 0..1023, first) + weight converts + wp1 pack
  //    + mcomb + inp GEMM (blocks 1024..3392) -- independent roots, pipe overlap.
  prep_k<<<3393,256,0,stream>>>(xyz, feat, W_pre, b_pre, WQ, WK, WV, Wa1, Wa2, Wp2,
                                Wproj, W_post, Wp1,
                                wqkvb, wa1b, wa2b, wp2b, wprojb, wpostb,
                                wp1pk, mcombb, idxw, inp);
  // 2) q: qa = ln(inp@WQ.T)@Wa1.T ; k: ka = ...; v: lnv slice  (BK=64)
  gemmlnqa_k<<<dim3(256,1,3),512,0,stream>>>(inp, wqkvb, wa1b, qab, kab, lnqkv, g_dm, b_dm);
  // 3) attention: 2048 blocks x 1024 threads, 8 queries/block
  attn_k<<<2048,1024,0,stream>>>(xyz,idxw,lnqkv,qab,kab,mcombb,wp2b,wa2b,wp1pk,resb);
  // 4) out = ln( ln(res@Wproj.T)@Wpost.T + b_post )*g+b + feat  (BK=64)
  projpost_k<<<256,512,0,stream>>>(resb, wprojb, wpostb, b_post, g_dm, b_dm, g_dp, b_dp,
                                   feat, out);
}